// Round 1
// baseline (5728.749 us; speedup 1.0000x reference)
//
#include <hip/hip_runtime.h>
#include <math.h>

// Problem constants (match reference)
#define NTOT  24576      // B*N nodes
#define NB    8
#define NPB   3072       // nodes per batch
#define HD    64
#define KNN   20

__device__ __forceinline__ float elu_f(float x){ return x > 0.f ? x : expm1f(x); }
__device__ __forceinline__ float lrelu_f(float x){ return x > 0.f ? x : 0.2f*x; }

// ---------------- encoder: x(NT,8) -> elu(elu(x@W1+b1)@W2+b2) (NT,64) ----------------
__global__ __launch_bounds__(256) void enc_kernel(const float* __restrict__ x,
    const float* __restrict__ W1, const float* __restrict__ b1,
    const float* __restrict__ W2, const float* __restrict__ b2,
    float* __restrict__ out){
  __shared__ float sW1[256], sb1[32], sW2[2048], sb2[64];
  int t = threadIdx.x;
  if (t < 256) sW1[t] = W1[t];
  for (int i = t; i < 2048; i += 256) sW2[i] = W2[i];
  if (t < 32) sb1[t] = b1[t];
  if (t < 64) sb2[t] = b2[t];
  __syncthreads();
  int n = blockIdx.x*256 + t;
  const float4* xp = (const float4*)(x + (size_t)n*8);
  float4 x0 = xp[0], x1 = xp[1];
  float xi[8] = {x0.x,x0.y,x0.z,x0.w,x1.x,x1.y,x1.z,x1.w};
  float h1[32];
  #pragma unroll
  for (int j = 0; j < 32; j++){
    float a = sb1[j];
    #pragma unroll
    for (int d = 0; d < 8; d++) a = fmaf(xi[d], sW1[d*32+j], a);
    h1[j] = elu_f(a);
  }
  float4* op = (float4*)(out + (size_t)n*64);
  #pragma unroll
  for (int c4 = 0; c4 < 16; c4++){
    float a0 = sb2[c4*4+0], a1 = sb2[c4*4+1], a2 = sb2[c4*4+2], a3 = sb2[c4*4+3];
    #pragma unroll
    for (int d = 0; d < 32; d++){
      float hd = h1[d];
      float4 wv = *(const float4*)&sW2[d*64 + c4*4];
      a0 = fmaf(hd, wv.x, a0); a1 = fmaf(hd, wv.y, a1);
      a2 = fmaf(hd, wv.z, a2); a3 = fmaf(hd, wv.w, a3);
    }
    float4 o; o.x=elu_f(a0); o.y=elu_f(a1); o.z=elu_f(a2); o.w=elu_f(a3);
    op[c4] = o;
  }
}

// ---------------- squared norms ----------------
__global__ __launch_bounds__(256) void sq_kernel(const float* __restrict__ f, float* __restrict__ sq){
  int n = blockIdx.x*256 + threadIdx.x;
  const float4* p = (const float4*)(f + (size_t)n*64);
  float s = 0.f;
  #pragma unroll
  for (int i = 0; i < 16; i++){
    float4 v = p[i];
    s = fmaf(v.x,v.x,s); s = fmaf(v.y,v.y,s); s = fmaf(v.z,v.z,s); s = fmaf(v.w,v.w,s);
  }
  sq[n] = s;
}

// ---------------- kNN: GEMM-tiled distances + per-row stable top-20 ----------------
// grid = NB * (NPB/64) blocks of 256 threads. Block handles 64 query rows of one batch,
// scans all 3072 candidates in 64-wide tiles. score = sq[m] - 2*dot (same order as d).
__global__ __launch_bounds__(256) void knn_kernel(const float* __restrict__ feat,
    const float* __restrict__ sqn, int* __restrict__ idxout){
  int b  = blockIdx.x / 48;
  int q0 = (blockIdx.x % 48) * 64;
  int t  = threadIdx.x;
  int ty = t >> 4, tx = t & 15;
  __shared__ float As[64][64];   // [dim][query]
  __shared__ float Bs[64][64];   // [dim][cand]
  __shared__ float Ds[64][68];   // dot tile, padded
  __shared__ float ssq[64];
  const float* fb = feat + (size_t)b*NPB*HD;
  {
    int r = t >> 2, dc = (t & 3)*16;
    const float4* src = (const float4*)(fb + (size_t)(q0 + r)*HD + dc);
    #pragma unroll
    for (int i = 0; i < 4; i++){
      float4 v = src[i]; int d = dc + i*4;
      As[d][r]=v.x; As[d+1][r]=v.y; As[d+2][r]=v.z; As[d+3][r]=v.w;
    }
  }
  float dist[KNN]; int didx[KNN];
  #pragma unroll
  for (int i = 0; i < KNN; i++){ dist[i] = 3.4e38f; didx[i] = 0; }
  int qloc = q0 + t;   // local query index owned by threads t<64 (selection phase)

  for (int m0 = 0; m0 < NPB; m0 += 64){
    __syncthreads();   // prev selection done; A staged (first iter)
    {
      int r = t >> 2, dc = (t & 3)*16;
      const float4* src = (const float4*)(fb + (size_t)(m0 + r)*HD + dc);
      #pragma unroll
      for (int i = 0; i < 4; i++){
        float4 v = src[i]; int d = dc + i*4;
        Bs[d][r]=v.x; Bs[d+1][r]=v.y; Bs[d+2][r]=v.z; Bs[d+3][r]=v.w;
      }
      if (t < 64) ssq[t] = sqn[(size_t)b*NPB + m0 + t];
    }
    __syncthreads();
    float acc[4][4];
    #pragma unroll
    for (int i = 0; i < 4; i++)
      #pragma unroll
      for (int j = 0; j < 4; j++) acc[i][j] = 0.f;
    #pragma unroll 4
    for (int d = 0; d < 64; d++){
      float4 av = *(const float4*)&As[d][ty*4];
      float4 bv = *(const float4*)&Bs[d][tx*4];
      acc[0][0]=fmaf(av.x,bv.x,acc[0][0]); acc[0][1]=fmaf(av.x,bv.y,acc[0][1]);
      acc[0][2]=fmaf(av.x,bv.z,acc[0][2]); acc[0][3]=fmaf(av.x,bv.w,acc[0][3]);
      acc[1][0]=fmaf(av.y,bv.x,acc[1][0]); acc[1][1]=fmaf(av.y,bv.y,acc[1][1]);
      acc[1][2]=fmaf(av.y,bv.z,acc[1][2]); acc[1][3]=fmaf(av.y,bv.w,acc[1][3]);
      acc[2][0]=fmaf(av.z,bv.x,acc[2][0]); acc[2][1]=fmaf(av.z,bv.y,acc[2][1]);
      acc[2][2]=fmaf(av.z,bv.z,acc[2][2]); acc[2][3]=fmaf(av.z,bv.w,acc[2][3]);
      acc[3][0]=fmaf(av.w,bv.x,acc[3][0]); acc[3][1]=fmaf(av.w,bv.y,acc[3][1]);
      acc[3][2]=fmaf(av.w,bv.z,acc[3][2]); acc[3][3]=fmaf(av.w,bv.w,acc[3][3]);
    }
    #pragma unroll
    for (int i = 0; i < 4; i++){
      float4 o; o.x=acc[i][0]; o.y=acc[i][1]; o.z=acc[i][2]; o.w=acc[i][3];
      *(float4*)&Ds[ty*4+i][tx*4] = o;
    }
    __syncthreads();
    if (t < 64){
      #pragma unroll 1
      for (int j = 0; j < 64; j++){
        int m = m0 + j;
        float s = fmaf(-2.f, Ds[t][j], ssq[j]);
        if (m == qloc) continue;          // diagonal (+1e9 in reference)
        if (s < dist[KNN-1]){             // stable insert (ties keep earlier index)
          #pragma unroll
          for (int k = KNN-1; k >= 1; k--){
            bool sh = s < dist[k-1];
            float nd = sh ? dist[k-1] : (s < dist[k] ? s : dist[k]);
            int   ni = sh ? didx[k-1] : (s < dist[k] ? m : didx[k]);
            dist[k] = nd; didx[k] = ni;
          }
          if (s < dist[0]){ dist[0] = s; didx[0] = m; }
        }
      }
    }
  }
  if (t < 64){
    int* op = idxout + (size_t)((size_t)b*NPB + q0 + t)*KNN;
    #pragma unroll
    for (int k = 0; k < KNN; k++) op[k] = b*NPB + didx[k];  // global node id
  }
}

// ---------------- edge-conv factorization: u = x@(Wt-Wb)+b, v = x@Wb ----------------
__global__ __launch_bounds__(256) void uv_kernel(const float* __restrict__ feat,
    const float* __restrict__ W, const float* __restrict__ cb,
    float* __restrict__ u, float* __restrict__ v){
  __shared__ float sW[128*64];
  int t = threadIdx.x;
  for (int i = t; i < 8192; i += 256) sW[i] = W[i];
  __syncthreads();
  int n = blockIdx.x*256 + t;
  float4 fv[16];
  const float4* fp = (const float4*)(feat + (size_t)n*64);
  #pragma unroll
  for (int i = 0; i < 16; i++) fv[i] = fp[i];
  float4* up = (float4*)(u + (size_t)n*64);
  float4* vp = (float4*)(v + (size_t)n*64);
  #pragma unroll 1
  for (int c4 = 0; c4 < 16; c4++){
    float ua0=0,ua1=0,ua2=0,ua3=0, vb0=0,vb1=0,vb2=0,vb3=0;
    #pragma unroll
    for (int d4 = 0; d4 < 16; d4++){
      float4 fq = fv[d4];
      #pragma unroll
      for (int dd = 0; dd < 4; dd++){
        int d = d4*4 + dd;
        float fd = dd==0?fq.x : dd==1?fq.y : dd==2?fq.z : fq.w;
        float4 wt = *(const float4*)&sW[d*64 + c4*4];
        float4 wb = *(const float4*)&sW[(64+d)*64 + c4*4];
        ua0=fmaf(fd,wt.x,ua0); ua1=fmaf(fd,wt.y,ua1); ua2=fmaf(fd,wt.z,ua2); ua3=fmaf(fd,wt.w,ua3);
        vb0=fmaf(fd,wb.x,vb0); vb1=fmaf(fd,wb.y,vb1); vb2=fmaf(fd,wb.z,vb2); vb3=fmaf(fd,wb.w,vb3);
      }
    }
    float4 cbv = *(const float4*)&cb[c4*4];
    float4 uo, vo;
    uo.x = cbv.x + ua0 - vb0; uo.y = cbv.y + ua1 - vb1;
    uo.z = cbv.z + ua2 - vb2; uo.w = cbv.w + ua3 - vb3;
    vo.x = vb0; vo.y = vb1; vo.z = vb2; vo.w = vb3;
    up[c4] = uo; vp[c4] = vo;
  }
}

// ---------------- max-pool over k neighbors + BN + residual (one wave per node) ----------------
__global__ __launch_bounds__(256) void pool_kernel(const float* __restrict__ u, const float* __restrict__ v,
    const int* __restrict__ idx, const float* __restrict__ resid,
    const float* __restrict__ bg, const float* __restrict__ bb,
    const float* __restrict__ bm, const float* __restrict__ bv,
    float* __restrict__ out){
  int gid = blockIdx.x*256 + threadIdx.x;
  int n = gid >> 6, lane = gid & 63;
  float uc = u[(size_t)n*64 + lane];
  float scale = bg[lane] / sqrtf(bv[lane] + 1e-5f);
  float bias  = bb[lane] - bm[lane]*scale;
  const int* ip = idx + (size_t)n*KNN;
  float acc = -3.4e38f;
  #pragma unroll 4
  for (int k = 0; k < KNN; k++){
    int j = ip[k];
    float s = uc + v[(size_t)j*64 + lane];
    acc = fmaxf(acc, fmaf(elu_f(s), scale, bias));
  }
  out[(size_t)n*64 + lane] = acc + resid[(size_t)n*64 + lane];
}

// ---------------- CSR build over dst (edges + self loops) ----------------
__global__ void deg_init(int* deg){ int i = blockIdx.x*256 + threadIdx.x; if (i < NTOT) deg[i] = 1; }
__global__ void deg_hist(const int* __restrict__ ei, int E, int* deg){
  int i = blockIdx.x*256 + threadIdx.x; if (i < E) atomicAdd(&deg[ei[E + i]], 1);
}
__global__ void scan_kernel(const int* __restrict__ deg, int* __restrict__ rowptr, int* __restrict__ cursor){
  __shared__ int part[256];
  int t = threadIdx.x;
  int base = t*96;
  int s = 0;
  for (int i = 0; i < 96; i++) s += deg[base + i];
  part[t] = s;
  __syncthreads();
  for (int off = 1; off < 256; off <<= 1){
    int xv = (t >= off) ? part[t - off] : 0;
    __syncthreads();
    part[t] += xv;
    __syncthreads();
  }
  int run = part[t] - s;   // exclusive prefix
  for (int i = 0; i < 96; i++){
    rowptr[base + i] = run; cursor[base + i] = run; run += deg[base + i];
  }
  if (t == 255) rowptr[NTOT] = run;
}
__global__ void scatter_kernel(const int* __restrict__ ei, int E, int* cursor, int* __restrict__ csr){
  int i = blockIdx.x*256 + threadIdx.x;
  if (i >= E + NTOT) return;
  int s, d;
  if (i < E){ s = ei[i]; d = ei[E + i]; } else { s = i - E; d = s; }
  int pos = atomicAdd(&cursor[d], 1);
  csr[pos] = s;
}

// ---------------- GAT: xh = x@W (NT,256), al_s/al_d per head ----------------
__global__ __launch_bounds__(256) void xh_kernel(const float* __restrict__ feat,
    const float* __restrict__ W, const float* __restrict__ asrc, const float* __restrict__ adst,
    float* __restrict__ xh, float* __restrict__ al){
  __shared__ float sW[64*128];
  __shared__ float sas[256], sad[256];
  int t = threadIdx.x;
  if (t < 256){ sas[t] = asrc[t]; sad[t] = adst[t]; }
  int n = blockIdx.x*256 + t;
  float4 fv[16];
  const float4* fp = (const float4*)(feat + (size_t)n*64);
  #pragma unroll
  for (int i = 0; i < 16; i++) fv[i] = fp[i];
  float4* xp = (float4*)(xh + (size_t)n*256);
  float* ap = al + (size_t)n*8;
  #pragma unroll 1
  for (int half = 0; half < 2; half++){
    __syncthreads();
    for (int i = t; i < 8192; i += 256){
      int d = i >> 7, c = i & 127;
      sW[i] = W[d*256 + half*128 + c];
    }
    __syncthreads();
    #pragma unroll 1
    for (int hh = 0; hh < 2; hh++){
      int h = half*2 + hh;
      float as_ = 0.f, ad_ = 0.f;
      #pragma unroll 1
      for (int cc = 0; cc < 64; cc += 4){
        int c  = h*64 + cc;        // global out col
        int cl = hh*64 + cc;       // local col in sW
        float a0=0,a1=0,a2=0,a3=0;
        #pragma unroll
        for (int d4 = 0; d4 < 16; d4++){
          float4 fq = fv[d4];
          #pragma unroll
          for (int dd = 0; dd < 4; dd++){
            int d = d4*4 + dd;
            float fd = dd==0?fq.x : dd==1?fq.y : dd==2?fq.z : fq.w;
            float4 wv = *(const float4*)&sW[d*128 + cl];
            a0=fmaf(fd,wv.x,a0); a1=fmaf(fd,wv.y,a1); a2=fmaf(fd,wv.z,a2); a3=fmaf(fd,wv.w,a3);
          }
        }
        float4 o; o.x=a0; o.y=a1; o.z=a2; o.w=a3;
        xp[c >> 2] = o;
        as_ = fmaf(a0, sas[c], fmaf(a1, sas[c+1], fmaf(a2, sas[c+2], fmaf(a3, sas[c+3], as_))));
        ad_ = fmaf(a0, sad[c], fmaf(a1, sad[c+1], fmaf(a2, sad[c+2], fmaf(a3, sad[c+3], ad_))));
      }
      ap[h] = as_; ap[4 + h] = ad_;
    }
  }
}

// ---------------- GAT aggregation: one wave per dst node, CSR edges ----------------
__global__ __launch_bounds__(256) void agg_kernel(const float* __restrict__ xh, const float* __restrict__ al,
    const int* __restrict__ rowptr, const int* __restrict__ csr,
    const float* __restrict__ resid, const float* __restrict__ bias,
    float* __restrict__ out){
  int gid = blockIdx.x*256 + threadIdx.x;
  int n = gid >> 6, lane = gid & 63;
  int rs = rowptr[n], re = rowptr[n+1];
  float4 ald = *(const float4*)(al + (size_t)n*8 + 4);
  float mx0=-3.4e38f, mx1=-3.4e38f, mx2=-3.4e38f, mx3=-3.4e38f;
  for (int e = rs; e < re; e++){
    int s = csr[e];
    float4 als = *(const float4*)(al + (size_t)s*8);
    mx0 = fmaxf(mx0, lrelu_f(als.x + ald.x));
    mx1 = fmaxf(mx1, lrelu_f(als.y + ald.y));
    mx2 = fmaxf(mx2, lrelu_f(als.z + ald.z));
    mx3 = fmaxf(mx3, lrelu_f(als.w + ald.w));
  }
  int h = lane >> 4, coff = (lane & 15)*4;
  float dx=0,dy=0,dz=0,dw=0;
  float ax=0,ay=0,az=0,aw=0;
  for (int e = rs; e < re; e++){
    int s = csr[e];
    float4 als = *(const float4*)(al + (size_t)s*8);
    float e0 = expf(lrelu_f(als.x + ald.x) - mx0);
    float e1 = expf(lrelu_f(als.y + ald.y) - mx1);
    float e2 = expf(lrelu_f(als.z + ald.z) - mx2);
    float e3 = expf(lrelu_f(als.w + ald.w) - mx3);
    dx += e0; dy += e1; dz += e2; dw += e3;
    float ah = h==0?e0 : h==1?e1 : h==2?e2 : e3;
    float4 xv = *(const float4*)(xh + (size_t)s*256 + h*64 + coff);
    ax = fmaf(ah, xv.x, ax); ay = fmaf(ah, xv.y, ay);
    az = fmaf(ah, xv.z, az); aw = fmaf(ah, xv.w, aw);
  }
  float den = h==0?dx : h==1?dy : h==2?dz : dw;
  float rinv = 1.f / (den + 1e-16f);
  float r0 = ax*rinv, r1 = ay*rinv, r2 = az*rinv, r3 = aw*rinv;
  r0 += __shfl_xor(r0, 16, 64); r1 += __shfl_xor(r1, 16, 64);
  r2 += __shfl_xor(r2, 16, 64); r3 += __shfl_xor(r3, 16, 64);
  r0 += __shfl_xor(r0, 32, 64); r1 += __shfl_xor(r1, 32, 64);
  r2 += __shfl_xor(r2, 32, 64); r3 += __shfl_xor(r3, 32, 64);
  if (lane < 16){
    float4 bs = *(const float4*)(bias + coff);
    float4 rv = *(const float4*)(resid + (size_t)n*64 + coff);
    float4 o;
    o.x = r0*0.25f + bs.x + rv.x; o.y = r1*0.25f + bs.y + rv.y;
    o.z = r2*0.25f + bs.z + rv.z; o.w = r3*0.25f + bs.w + rv.w;
    *(float4*)(out + (size_t)n*64 + coff) = o;
  }
}

// ---------------- output MLP: 64->64 elu ->32 elu ->8 ----------------
__global__ __launch_bounds__(256) void mlp_kernel(const float* __restrict__ feat,
    const float* __restrict__ W1, const float* __restrict__ b1,
    const float* __restrict__ W2, const float* __restrict__ b2,
    const float* __restrict__ W3, const float* __restrict__ b3,
    float* __restrict__ out){
  __shared__ float s1[4096], s2[2048], s3[256], t1[64], t2[32], t3[8];
  int t = threadIdx.x;
  for (int i = t; i < 4096; i += 256) s1[i] = W1[i];
  for (int i = t; i < 2048; i += 256) s2[i] = W2[i];
  if (t < 256) s3[t] = W3[t];
  if (t < 64) t1[t] = b1[t];
  if (t < 32) t2[t] = b2[t];
  if (t < 8)  t3[t] = b3[t];
  __syncthreads();
  int n = blockIdx.x*256 + t;
  float4 fv[16];
  const float4* fp = (const float4*)(feat + (size_t)n*64);
  #pragma unroll
  for (int i = 0; i < 16; i++) fv[i] = fp[i];
  float o1[64];
  #pragma unroll 1
  for (int c4 = 0; c4 < 16; c4++){
    float a0=t1[c4*4+0], a1=t1[c4*4+1], a2=t1[c4*4+2], a3=t1[c4*4+3];
    #pragma unroll
    for (int d4 = 0; d4 < 16; d4++){
      float4 fq = fv[d4];
      #pragma unroll
      for (int dd = 0; dd < 4; dd++){
        int d = d4*4 + dd;
        float fd = dd==0?fq.x : dd==1?fq.y : dd==2?fq.z : fq.w;
        float4 wv = *(const float4*)&s1[d*64 + c4*4];
        a0=fmaf(fd,wv.x,a0); a1=fmaf(fd,wv.y,a1); a2=fmaf(fd,wv.z,a2); a3=fmaf(fd,wv.w,a3);
      }
    }
    o1[c4*4+0]=elu_f(a0); o1[c4*4+1]=elu_f(a1); o1[c4*4+2]=elu_f(a2); o1[c4*4+3]=elu_f(a3);
  }
  float o2[32];
  #pragma unroll 1
  for (int c4 = 0; c4 < 8; c4++){
    float a0=t2[c4*4+0], a1=t2[c4*4+1], a2=t2[c4*4+2], a3=t2[c4*4+3];
    #pragma unroll
    for (int d = 0; d < 64; d++){
      float fd = o1[d];
      float4 wv = *(const float4*)&s2[d*32 + c4*4];
      a0=fmaf(fd,wv.x,a0); a1=fmaf(fd,wv.y,a1); a2=fmaf(fd,wv.z,a2); a3=fmaf(fd,wv.w,a3);
    }
    o2[c4*4+0]=elu_f(a0); o2[c4*4+1]=elu_f(a1); o2[c4*4+2]=elu_f(a2); o2[c4*4+3]=elu_f(a3);
  }
  float4* op = (float4*)(out + (size_t)n*8);
  #pragma unroll
  for (int c4 = 0; c4 < 2; c4++){
    float a0=t3[c4*4+0], a1=t3[c4*4+1], a2=t3[c4*4+2], a3=t3[c4*4+3];
    #pragma unroll
    for (int d = 0; d < 32; d++){
      float fd = o2[d];
      float4 wv = *(const float4*)&s3[d*8 + c4*4];
      a0=fmaf(fd,wv.x,a0); a1=fmaf(fd,wv.y,a1); a2=fmaf(fd,wv.z,a2); a3=fmaf(fd,wv.w,a3);
    }
    float4 o; o.x=a0; o.y=a1; o.z=a2; o.w=a3;
    op[c4] = o;
  }
}

extern "C" void kernel_launch(void* const* d_in, const int* in_sizes, int n_in,
                              void* d_out, int out_size, void* d_ws, size_t ws_size,
                              hipStream_t stream){
  (void)n_in; (void)out_size; (void)ws_size;
  const float* x     = (const float*)d_in[0];
  // d_in[1] (batch) unused: batch b = node / NPB by construction
  const int*   ei    = (const int*)d_in[2];
  const int    E     = in_sizes[2] / 2;
  const float* encW1 = (const float*)d_in[3];
  const float* encb1 = (const float*)d_in[4];
  const float* encW2 = (const float*)d_in[5];
  const float* encb2 = (const float*)d_in[6];
  const float* convW = (const float*)d_in[7];
  const float* convb = (const float*)d_in[8];
  const float* bng   = (const float*)d_in[9];
  const float* bnb   = (const float*)d_in[10];
  const float* bnm   = (const float*)d_in[11];
  const float* bnv   = (const float*)d_in[12];
  const float* gatW  = (const float*)d_in[13];
  const float* gatas = (const float*)d_in[14];
  const float* gatad = (const float*)d_in[15];
  const float* gatb  = (const float*)d_in[16];
  const float* oW1   = (const float*)d_in[17];
  const float* ob1   = (const float*)d_in[18];
  const float* oW2   = (const float*)d_in[19];
  const float* ob2   = (const float*)d_in[20];
  const float* oW3   = (const float*)d_in[21];
  const float* ob3   = (const float*)d_in[22];

  char* wp = (char*)d_ws;
  auto alloc = [&](size_t bytes)->void*{
    void* p = (void*)wp; wp += (bytes + 255) & ~((size_t)255); return p;
  };
  float* fA     = (float*)alloc((size_t)NTOT*64*4);
  float* fB     = (float*)alloc((size_t)NTOT*64*4);
  float* ubuf   = (float*)alloc((size_t)NTOT*64*4);
  float* vbuf   = (float*)alloc((size_t)NTOT*64*4);
  float* sqb    = (float*)alloc((size_t)NTOT*4);
  int*   idxb   = (int*)  alloc((size_t)NTOT*KNN*4);
  float* xhb    = (float*)alloc((size_t)NTOT*256*4);
  float* alb    = (float*)alloc((size_t)NTOT*8*4);
  int*   degb   = (int*)  alloc((size_t)NTOT*4);
  int*   rowptr = (int*)  alloc((size_t)(NTOT+1)*4);
  int*   cursor = (int*)  alloc((size_t)NTOT*4);
  int*   csr    = (int*)  alloc((size_t)(E+NTOT)*4);
  // total ws usage ~56 MB

  enc_kernel<<<96,256,0,stream>>>(x, encW1, encb1, encW2, encb2, fA);
  float* cur = fA; float* nxt = fB;
  for (int l = 0; l < 3; l++){
    sq_kernel  <<<96,  256,0,stream>>>(cur, sqb);
    knn_kernel <<<384, 256,0,stream>>>(cur, sqb, idxb);
    uv_kernel  <<<96,  256,0,stream>>>(cur, convW + (size_t)l*8192, convb + l*64, ubuf, vbuf);
    pool_kernel<<<6144,256,0,stream>>>(ubuf, vbuf, idxb, cur,
                                       bng + l*64, bnb + l*64, bnm + l*64, bnv + l*64, nxt);
    float* tmp = cur; cur = nxt; nxt = tmp;
  }
  deg_init   <<<96,            256,0,stream>>>(degb);
  deg_hist   <<<(E+255)/256,   256,0,stream>>>(ei, E, degb);
  scan_kernel<<<1,             256,0,stream>>>(degb, rowptr, cursor);
  scatter_kernel<<<(E+NTOT+255)/256,256,0,stream>>>(ei, E, cursor, csr);
  for (int l = 0; l < 2; l++){
    xh_kernel <<<96,  256,0,stream>>>(cur, gatW + (size_t)l*16384, gatas + l*256, gatad + l*256, xhb, alb);
    agg_kernel<<<6144,256,0,stream>>>(xhb, alb, rowptr, csr, cur, gatb + l*64, nxt);
    float* tmp = cur; cur = nxt; nxt = tmp;
  }
  mlp_kernel<<<96,256,0,stream>>>(cur, oW1, ob1, oW2, ob2, oW3, ob3, (float*)d_out);
}

// Round 2
// 3059.108 us; speedup vs baseline: 1.8727x; 1.8727x over previous
//
#include <hip/hip_runtime.h>
#include <math.h>

// Problem constants (match reference)
#define NTOT  24576      // B*N nodes
#define NB    8
#define NPB   3072       // nodes per batch
#define HD    64
#define KNN   20

__device__ __forceinline__ float elu_f(float x){ return x > 0.f ? x : expm1f(x); }
__device__ __forceinline__ float lrelu_f(float x){ return x > 0.f ? x : 0.2f*x; }

// ---------------- encoder: x(NT,8) -> elu(elu(x@W1+b1)@W2+b2) (NT,64) ----------------
__global__ __launch_bounds__(256) void enc_kernel(const float* __restrict__ x,
    const float* __restrict__ W1, const float* __restrict__ b1,
    const float* __restrict__ W2, const float* __restrict__ b2,
    float* __restrict__ out){
  __shared__ float sW1[256], sb1[32], sW2[2048], sb2[64];
  int t = threadIdx.x;
  if (t < 256) sW1[t] = W1[t];
  for (int i = t; i < 2048; i += 256) sW2[i] = W2[i];
  if (t < 32) sb1[t] = b1[t];
  if (t < 64) sb2[t] = b2[t];
  __syncthreads();
  int n = blockIdx.x*256 + t;
  const float4* xp = (const float4*)(x + (size_t)n*8);
  float4 x0 = xp[0], x1 = xp[1];
  float xi[8] = {x0.x,x0.y,x0.z,x0.w,x1.x,x1.y,x1.z,x1.w};
  float h1[32];
  #pragma unroll
  for (int j = 0; j < 32; j++){
    float a = sb1[j];
    #pragma unroll
    for (int d = 0; d < 8; d++) a = fmaf(xi[d], sW1[d*32+j], a);
    h1[j] = elu_f(a);
  }
  float4* op = (float4*)(out + (size_t)n*64);
  #pragma unroll
  for (int c4 = 0; c4 < 16; c4++){
    float a0 = sb2[c4*4+0], a1 = sb2[c4*4+1], a2 = sb2[c4*4+2], a3 = sb2[c4*4+3];
    #pragma unroll
    for (int d = 0; d < 32; d++){
      float hd = h1[d];
      float4 wv = *(const float4*)&sW2[d*64 + c4*4];
      a0 = fmaf(hd, wv.x, a0); a1 = fmaf(hd, wv.y, a1);
      a2 = fmaf(hd, wv.z, a2); a3 = fmaf(hd, wv.w, a3);
    }
    float4 o; o.x=elu_f(a0); o.y=elu_f(a1); o.z=elu_f(a2); o.w=elu_f(a3);
    op[c4] = o;
  }
}

// ---------------- squared norms ----------------
__global__ __launch_bounds__(256) void sq_kernel(const float* __restrict__ f, float* __restrict__ sq){
  int n = blockIdx.x*256 + threadIdx.x;
  const float4* p = (const float4*)(f + (size_t)n*64);
  float s = 0.f;
  #pragma unroll
  for (int i = 0; i < 16; i++){
    float4 v = p[i];
    s = fmaf(v.x,v.x,s); s = fmaf(v.y,v.y,s); s = fmaf(v.z,v.z,s); s = fmaf(v.w,v.w,s);
  }
  sq[n] = s;
}

// ---------------- distance GEMM: s[q][m] = sq[m] - 2*dot(q,m), 128x128 tiles ----------------
// grid = dim3(24, 24, nbat), 256 threads, 8x8 micro-tile per thread.
__global__ __launch_bounds__(256) void dist_kernel(const float* __restrict__ feat,
    const float* __restrict__ sqn, float* __restrict__ D){
  int b  = blockIdx.z;
  int m0 = blockIdx.x * 128;
  int q0 = blockIdx.y * 128;
  const float* fb = feat + (size_t)b*NPB*HD;
  float* Db = D + (size_t)b*NPB*NPB;
  __shared__ float As[64][128];   // [dim][query]
  __shared__ float Bs[64][128];   // [dim][cand]
  int t = threadIdx.x;
  {
    int r = t >> 1, dc = (t & 1) * 32;
    const float4* pa = (const float4*)(fb + (size_t)(q0 + r)*HD + dc);
    const float4* pb = (const float4*)(fb + (size_t)(m0 + r)*HD + dc);
    #pragma unroll
    for (int i = 0; i < 8; i++){
      float4 va = pa[i], vb = pb[i];
      int d = dc + i*4;
      As[d][r]=va.x; As[d+1][r]=va.y; As[d+2][r]=va.z; As[d+3][r]=va.w;
      Bs[d][r]=vb.x; Bs[d+1][r]=vb.y; Bs[d+2][r]=vb.z; Bs[d+3][r]=vb.w;
    }
  }
  __syncthreads();
  int tx = t & 15, ty = t >> 4;
  float acc[8][8];
  #pragma unroll
  for (int i = 0; i < 8; i++)
    #pragma unroll
    for (int j = 0; j < 8; j++) acc[i][j] = 0.f;
  #pragma unroll 2
  for (int d = 0; d < 64; d++){
    float af[8], bf[8];
    *(float4*)&af[0] = *(const float4*)&As[d][ty*8];
    *(float4*)&af[4] = *(const float4*)&As[d][ty*8+4];
    *(float4*)&bf[0] = *(const float4*)&Bs[d][tx*8];
    *(float4*)&bf[4] = *(const float4*)&Bs[d][tx*8+4];
    #pragma unroll
    for (int i = 0; i < 8; i++)
      #pragma unroll
      for (int j = 0; j < 8; j++)
        acc[i][j] = fmaf(af[i], bf[j], acc[i][j]);
  }
  const float4* sp = (const float4*)(sqn + (size_t)b*NPB + m0 + tx*8);
  float4 sq0 = sp[0], sq1 = sp[1];
  float sqv[8] = {sq0.x,sq0.y,sq0.z,sq0.w,sq1.x,sq1.y,sq1.z,sq1.w};
  #pragma unroll
  for (int i = 0; i < 8; i++){
    float* orow = Db + (size_t)(q0 + ty*8 + i)*NPB + m0 + tx*8;
    float4 o0, o1;
    o0.x = fmaf(-2.f, acc[i][0], sqv[0]); o0.y = fmaf(-2.f, acc[i][1], sqv[1]);
    o0.z = fmaf(-2.f, acc[i][2], sqv[2]); o0.w = fmaf(-2.f, acc[i][3], sqv[3]);
    o1.x = fmaf(-2.f, acc[i][4], sqv[4]); o1.y = fmaf(-2.f, acc[i][5], sqv[5]);
    o1.z = fmaf(-2.f, acc[i][6], sqv[6]); o1.w = fmaf(-2.f, acc[i][7], sqv[7]);
    *(float4*)orow = o0; *((float4*)orow + 1) = o1;
  }
}

// ---------------- top-20 select: one wave per query row ----------------
// Each lane owns candidates m = lane*4 + c*256 + e (12 float4 loads), keeps a
// private sorted top-20, then 20 rounds of lex-min (d, idx) wave reduction.
__global__ __launch_bounds__(256) void select_kernel(const float* __restrict__ D,
    int* __restrict__ idxout, int qbase){
  int w = blockIdx.x*4 + (int)(threadIdx.x >> 6);
  int lane = threadIdx.x & 63;
  int g = qbase + w;                 // global query node id
  int ql = g % NPB;                  // local (within-batch) query index
  int nbase = g - ql;                // batch base node id
  const float* row = D + (size_t)w * NPB;
  float dl[KNN]; int il[KNN];
  #pragma unroll
  for (int k = 0; k < KNN; k++){ dl[k] = 3.4e38f; il[k] = 0x7fffffff; }
  #pragma unroll 1
  for (int c = 0; c < 12; c++){
    int mbase = c*256 + lane*4;
    float4 v = *(const float4*)(row + mbase);
    #pragma unroll
    for (int e = 0; e < 4; e++){
      int m = mbase + e;
      float s = (e==0)?v.x:(e==1)?v.y:(e==2)?v.z:v.w;
      if (m == ql) continue;                    // diagonal
      if (s < dl[KNN-1]){                       // stable sorted insert
        #pragma unroll
        for (int k = KNN-1; k >= 1; k--){
          bool c1 = s < dl[k-1];
          bool c0 = s < dl[k];
          dl[k] = c1 ? dl[k-1] : (c0 ? s : dl[k]);
          il[k] = c1 ? il[k-1] : (c0 ? m : il[k]);
        }
        if (s < dl[0]){ dl[0] = s; il[0] = m; }
      }
    }
  }
  int res = 0;
  #pragma unroll 1
  for (int r = 0; r < KNN; r++){
    float d = dl[0]; int i = il[0];
    #pragma unroll
    for (int off = 1; off < 64; off <<= 1){
      float od = __shfl_xor(d, off, 64);
      int   oi = __shfl_xor(i, off, 64);
      if (od < d || (od == d && oi < i)){ d = od; i = oi; }
    }
    if (lane == r) res = i;
    if (il[0] == i){                 // winner lane pops its head (i unique per lane)
      #pragma unroll
      for (int k = 0; k < KNN-1; k++){ dl[k] = dl[k+1]; il[k] = il[k+1]; }
      dl[KNN-1] = 3.4e38f; il[KNN-1] = 0x7fffffff;
    }
  }
  if (lane < KNN) idxout[(size_t)g*KNN + lane] = nbase + res;
}

// ---------------- legacy fused kNN (fallback when workspace too small) ----------------
__global__ __launch_bounds__(256) void knn_kernel(const float* __restrict__ feat,
    const float* __restrict__ sqn, int* __restrict__ idxout){
  int b  = blockIdx.x / 48;
  int q0 = (blockIdx.x % 48) * 64;
  int t  = threadIdx.x;
  int ty = t >> 4, tx = t & 15;
  __shared__ float As[64][64];
  __shared__ float Bs[64][64];
  __shared__ float Ds[64][68];
  __shared__ float ssq[64];
  const float* fb = feat + (size_t)b*NPB*HD;
  {
    int r = t >> 2, dc = (t & 3)*16;
    const float4* src = (const float4*)(fb + (size_t)(q0 + r)*HD + dc);
    #pragma unroll
    for (int i = 0; i < 4; i++){
      float4 v = src[i]; int d = dc + i*4;
      As[d][r]=v.x; As[d+1][r]=v.y; As[d+2][r]=v.z; As[d+3][r]=v.w;
    }
  }
  float dist[KNN]; int didx[KNN];
  #pragma unroll
  for (int i = 0; i < KNN; i++){ dist[i] = 3.4e38f; didx[i] = 0; }
  int qloc = q0 + t;
  for (int m0 = 0; m0 < NPB; m0 += 64){
    __syncthreads();
    {
      int r = t >> 2, dc = (t & 3)*16;
      const float4* src = (const float4*)(fb + (size_t)(m0 + r)*HD + dc);
      #pragma unroll
      for (int i = 0; i < 4; i++){
        float4 v = src[i]; int d = dc + i*4;
        Bs[d][r]=v.x; Bs[d+1][r]=v.y; Bs[d+2][r]=v.z; Bs[d+3][r]=v.w;
      }
      if (t < 64) ssq[t] = sqn[(size_t)b*NPB + m0 + t];
    }
    __syncthreads();
    float acc[4][4];
    #pragma unroll
    for (int i = 0; i < 4; i++)
      #pragma unroll
      for (int j = 0; j < 4; j++) acc[i][j] = 0.f;
    #pragma unroll 4
    for (int d = 0; d < 64; d++){
      float4 av = *(const float4*)&As[d][ty*4];
      float4 bv = *(const float4*)&Bs[d][tx*4];
      acc[0][0]=fmaf(av.x,bv.x,acc[0][0]); acc[0][1]=fmaf(av.x,bv.y,acc[0][1]);
      acc[0][2]=fmaf(av.x,bv.z,acc[0][2]); acc[0][3]=fmaf(av.x,bv.w,acc[0][3]);
      acc[1][0]=fmaf(av.y,bv.x,acc[1][0]); acc[1][1]=fmaf(av.y,bv.y,acc[1][1]);
      acc[1][2]=fmaf(av.y,bv.z,acc[1][2]); acc[1][3]=fmaf(av.y,bv.w,acc[1][3]);
      acc[2][0]=fmaf(av.z,bv.x,acc[2][0]); acc[2][1]=fmaf(av.z,bv.y,acc[2][1]);
      acc[2][2]=fmaf(av.z,bv.z,acc[2][2]); acc[2][3]=fmaf(av.z,bv.w,acc[2][3]);
      acc[3][0]=fmaf(av.w,bv.x,acc[3][0]); acc[3][1]=fmaf(av.w,bv.y,acc[3][1]);
      acc[3][2]=fmaf(av.w,bv.z,acc[3][2]); acc[3][3]=fmaf(av.w,bv.w,acc[3][3]);
    }
    #pragma unroll
    for (int i = 0; i < 4; i++){
      float4 o; o.x=acc[i][0]; o.y=acc[i][1]; o.z=acc[i][2]; o.w=acc[i][3];
      *(float4*)&Ds[ty*4+i][tx*4] = o;
    }
    __syncthreads();
    if (t < 64){
      #pragma unroll 1
      for (int j = 0; j < 64; j++){
        int m = m0 + j;
        float s = fmaf(-2.f, Ds[t][j], ssq[j]);
        if (m == qloc) continue;
        if (s < dist[KNN-1]){
          #pragma unroll
          for (int k = KNN-1; k >= 1; k--){
            bool sh = s < dist[k-1];
            float nd = sh ? dist[k-1] : (s < dist[k] ? s : dist[k]);
            int   ni = sh ? didx[k-1] : (s < dist[k] ? m : didx[k]);
            dist[k] = nd; didx[k] = ni;
          }
          if (s < dist[0]){ dist[0] = s; didx[0] = m; }
        }
      }
    }
  }
  if (t < 64){
    int* op = idxout + (size_t)((size_t)b*NPB + q0 + t)*KNN;
    #pragma unroll
    for (int k = 0; k < KNN; k++) op[k] = b*NPB + didx[k];
  }
}

// ---------------- edge-conv factorization: u = x@(Wt-Wb)+b, v = x@Wb ----------------
__global__ __launch_bounds__(256) void uv_kernel(const float* __restrict__ feat,
    const float* __restrict__ W, const float* __restrict__ cb,
    float* __restrict__ u, float* __restrict__ v){
  __shared__ float sW[128*64];
  int t = threadIdx.x;
  for (int i = t; i < 8192; i += 256) sW[i] = W[i];
  __syncthreads();
  int n = blockIdx.x*256 + t;
  float4 fv[16];
  const float4* fp = (const float4*)(feat + (size_t)n*64);
  #pragma unroll
  for (int i = 0; i < 16; i++) fv[i] = fp[i];
  float4* up = (float4*)(u + (size_t)n*64);
  float4* vp = (float4*)(v + (size_t)n*64);
  #pragma unroll 1
  for (int c4 = 0; c4 < 16; c4++){
    float ua0=0,ua1=0,ua2=0,ua3=0, vb0=0,vb1=0,vb2=0,vb3=0;
    #pragma unroll
    for (int d4 = 0; d4 < 16; d4++){
      float4 fq = fv[d4];
      #pragma unroll
      for (int dd = 0; dd < 4; dd++){
        int d = d4*4 + dd;
        float fd = dd==0?fq.x : dd==1?fq.y : dd==2?fq.z : fq.w;
        float4 wt = *(const float4*)&sW[d*64 + c4*4];
        float4 wb = *(const float4*)&sW[(64+d)*64 + c4*4];
        ua0=fmaf(fd,wt.x,ua0); ua1=fmaf(fd,wt.y,ua1); ua2=fmaf(fd,wt.z,ua2); ua3=fmaf(fd,wt.w,ua3);
        vb0=fmaf(fd,wb.x,vb0); vb1=fmaf(fd,wb.y,vb1); vb2=fmaf(fd,wb.z,vb2); vb3=fmaf(fd,wb.w,vb3);
      }
    }
    float4 cbv = *(const float4*)&cb[c4*4];
    float4 uo, vo;
    uo.x = cbv.x + ua0 - vb0; uo.y = cbv.y + ua1 - vb1;
    uo.z = cbv.z + ua2 - vb2; uo.w = cbv.w + ua3 - vb3;
    vo.x = vb0; vo.y = vb1; vo.z = vb2; vo.w = vb3;
    up[c4] = uo; vp[c4] = vo;
  }
}

// ---------------- max-pool over k neighbors + BN + residual (one wave per node) ----------------
__global__ __launch_bounds__(256) void pool_kernel(const float* __restrict__ u, const float* __restrict__ v,
    const int* __restrict__ idx, const float* __restrict__ resid,
    const float* __restrict__ bg, const float* __restrict__ bb,
    const float* __restrict__ bm, const float* __restrict__ bv,
    float* __restrict__ out){
  int gid = blockIdx.x*256 + threadIdx.x;
  int n = gid >> 6, lane = gid & 63;
  float uc = u[(size_t)n*64 + lane];
  float scale = bg[lane] / sqrtf(bv[lane] + 1e-5f);
  float bias  = bb[lane] - bm[lane]*scale;
  const int* ip = idx + (size_t)n*KNN;
  float acc = -3.4e38f;
  #pragma unroll 4
  for (int k = 0; k < KNN; k++){
    int j = ip[k];
    float s = uc + v[(size_t)j*64 + lane];
    acc = fmaxf(acc, fmaf(elu_f(s), scale, bias));
  }
  out[(size_t)n*64 + lane] = acc + resid[(size_t)n*64 + lane];
}

// ---------------- CSR build over dst (edges + self loops) ----------------
__global__ void deg_init(int* deg){ int i = blockIdx.x*256 + threadIdx.x; if (i < NTOT) deg[i] = 1; }
__global__ void deg_hist(const int* __restrict__ ei, int E, int* deg){
  int i = blockIdx.x*256 + threadIdx.x; if (i < E) atomicAdd(&deg[ei[E + i]], 1);
}
__global__ void scan_kernel(const int* __restrict__ deg, int* __restrict__ rowptr, int* __restrict__ cursor){
  __shared__ int part[256];
  int t = threadIdx.x;
  int base = t*96;
  int s = 0;
  for (int i = 0; i < 96; i++) s += deg[base + i];
  part[t] = s;
  __syncthreads();
  for (int off = 1; off < 256; off <<= 1){
    int xv = (t >= off) ? part[t - off] : 0;
    __syncthreads();
    part[t] += xv;
    __syncthreads();
  }
  int run = part[t] - s;
  for (int i = 0; i < 96; i++){
    rowptr[base + i] = run; cursor[base + i] = run; run += deg[base + i];
  }
  if (t == 255) rowptr[NTOT] = run;
}
__global__ void scatter_kernel(const int* __restrict__ ei, int E, int* cursor, int* __restrict__ csr){
  int i = blockIdx.x*256 + threadIdx.x;
  if (i >= E + NTOT) return;
  int s, d;
  if (i < E){ s = ei[i]; d = ei[E + i]; } else { s = i - E; d = s; }
  int pos = atomicAdd(&cursor[d], 1);
  csr[pos] = s;
}

// ---------------- GAT: xh = x@W (NT,256), al_s/al_d per head ----------------
__global__ __launch_bounds__(256) void xh_kernel(const float* __restrict__ feat,
    const float* __restrict__ W, const float* __restrict__ asrc, const float* __restrict__ adst,
    float* __restrict__ xh, float* __restrict__ al){
  __shared__ float sW[64*128];
  __shared__ float sas[256], sad[256];
  int t = threadIdx.x;
  if (t < 256){ sas[t] = asrc[t]; sad[t] = adst[t]; }
  int n = blockIdx.x*256 + t;
  float4 fv[16];
  const float4* fp = (const float4*)(feat + (size_t)n*64);
  #pragma unroll
  for (int i = 0; i < 16; i++) fv[i] = fp[i];
  float4* xp = (float4*)(xh + (size_t)n*256);
  float* ap = al + (size_t)n*8;
  #pragma unroll 1
  for (int half = 0; half < 2; half++){
    __syncthreads();
    for (int i = t; i < 8192; i += 256){
      int d = i >> 7, c = i & 127;
      sW[i] = W[d*256 + half*128 + c];
    }
    __syncthreads();
    #pragma unroll 1
    for (int hh = 0; hh < 2; hh++){
      int h = half*2 + hh;
      float as_ = 0.f, ad_ = 0.f;
      #pragma unroll 1
      for (int cc = 0; cc < 64; cc += 4){
        int c  = h*64 + cc;
        int cl = hh*64 + cc;
        float a0=0,a1=0,a2=0,a3=0;
        #pragma unroll
        for (int d4 = 0; d4 < 16; d4++){
          float4 fq = fv[d4];
          #pragma unroll
          for (int dd = 0; dd < 4; dd++){
            int d = d4*4 + dd;
            float fd = dd==0?fq.x : dd==1?fq.y : dd==2?fq.z : fq.w;
            float4 wv = *(const float4*)&sW[d*128 + cl];
            a0=fmaf(fd,wv.x,a0); a1=fmaf(fd,wv.y,a1); a2=fmaf(fd,wv.z,a2); a3=fmaf(fd,wv.w,a3);
          }
        }
        float4 o; o.x=a0; o.y=a1; o.z=a2; o.w=a3;
        xp[c >> 2] = o;
        as_ = fmaf(a0, sas[c], fmaf(a1, sas[c+1], fmaf(a2, sas[c+2], fmaf(a3, sas[c+3], as_))));
        ad_ = fmaf(a0, sad[c], fmaf(a1, sad[c+1], fmaf(a2, sad[c+2], fmaf(a3, sad[c+3], ad_))));
      }
      ap[h] = as_; ap[4 + h] = ad_;
    }
  }
}

// ---------------- GAT aggregation: one wave per dst node, CSR edges ----------------
__global__ __launch_bounds__(256) void agg_kernel(const float* __restrict__ xh, const float* __restrict__ al,
    const int* __restrict__ rowptr, const int* __restrict__ csr,
    const float* __restrict__ resid, const float* __restrict__ bias,
    float* __restrict__ out){
  int gid = blockIdx.x*256 + threadIdx.x;
  int n = gid >> 6, lane = gid & 63;
  int rs = rowptr[n], re = rowptr[n+1];
  float4 ald = *(const float4*)(al + (size_t)n*8 + 4);
  float mx0=-3.4e38f, mx1=-3.4e38f, mx2=-3.4e38f, mx3=-3.4e38f;
  for (int e = rs; e < re; e++){
    int s = csr[e];
    float4 als = *(const float4*)(al + (size_t)s*8);
    mx0 = fmaxf(mx0, lrelu_f(als.x + ald.x));
    mx1 = fmaxf(mx1, lrelu_f(als.y + ald.y));
    mx2 = fmaxf(mx2, lrelu_f(als.z + ald.z));
    mx3 = fmaxf(mx3, lrelu_f(als.w + ald.w));
  }
  int h = lane >> 4, coff = (lane & 15)*4;
  float dx=0,dy=0,dz=0,dw=0;
  float ax=0,ay=0,az=0,aw=0;
  for (int e = rs; e < re; e++){
    int s = csr[e];
    float4 als = *(const float4*)(al + (size_t)s*8);
    float e0 = expf(lrelu_f(als.x + ald.x) - mx0);
    float e1 = expf(lrelu_f(als.y + ald.y) - mx1);
    float e2 = expf(lrelu_f(als.z + ald.z) - mx2);
    float e3 = expf(lrelu_f(als.w + ald.w) - mx3);
    dx += e0; dy += e1; dz += e2; dw += e3;
    float ah = h==0?e0 : h==1?e1 : h==2?e2 : e3;
    float4 xv = *(const float4*)(xh + (size_t)s*256 + h*64 + coff);
    ax = fmaf(ah, xv.x, ax); ay = fmaf(ah, xv.y, ay);
    az = fmaf(ah, xv.z, az); aw = fmaf(ah, xv.w, aw);
  }
  float den = h==0?dx : h==1?dy : h==2?dz : dw;
  float rinv = 1.f / (den + 1e-16f);
  float r0 = ax*rinv, r1 = ay*rinv, r2 = az*rinv, r3 = aw*rinv;
  r0 += __shfl_xor(r0, 16, 64); r1 += __shfl_xor(r1, 16, 64);
  r2 += __shfl_xor(r2, 16, 64); r3 += __shfl_xor(r3, 16, 64);
  r0 += __shfl_xor(r0, 32, 64); r1 += __shfl_xor(r1, 32, 64);
  r2 += __shfl_xor(r2, 32, 64); r3 += __shfl_xor(r3, 32, 64);
  if (lane < 16){
    float4 bs = *(const float4*)(bias + coff);
    float4 rv = *(const float4*)(resid + (size_t)n*64 + coff);
    float4 o;
    o.x = r0*0.25f + bs.x + rv.x; o.y = r1*0.25f + bs.y + rv.y;
    o.z = r2*0.25f + bs.z + rv.z; o.w = r3*0.25f + bs.w + rv.w;
    *(float4*)(out + (size_t)n*64 + coff) = o;
  }
}

// ---------------- output MLP: 64->64 elu ->32 elu ->8 ----------------
__global__ __launch_bounds__(256) void mlp_kernel(const float* __restrict__ feat,
    const float* __restrict__ W1, const float* __restrict__ b1,
    const float* __restrict__ W2, const float* __restrict__ b2,
    const float* __restrict__ W3, const float* __restrict__ b3,
    float* __restrict__ out){
  __shared__ float s1[4096], s2[2048], s3[256], t1[64], t2[32], t3[8];
  int t = threadIdx.x;
  for (int i = t; i < 4096; i += 256) s1[i] = W1[i];
  for (int i = t; i < 2048; i += 256) s2[i] = W2[i];
  if (t < 256) s3[t] = W3[t];
  if (t < 64) t1[t] = b1[t];
  if (t < 32) t2[t] = b2[t];
  if (t < 8)  t3[t] = b3[t];
  __syncthreads();
  int n = blockIdx.x*256 + t;
  float4 fv[16];
  const float4* fp = (const float4*)(feat + (size_t)n*64);
  #pragma unroll
  for (int i = 0; i < 16; i++) fv[i] = fp[i];
  float o1[64];
  #pragma unroll 1
  for (int c4 = 0; c4 < 16; c4++){
    float a0=t1[c4*4+0], a1=t1[c4*4+1], a2=t1[c4*4+2], a3=t1[c4*4+3];
    #pragma unroll
    for (int d4 = 0; d4 < 16; d4++){
      float4 fq = fv[d4];
      #pragma unroll
      for (int dd = 0; dd < 4; dd++){
        int d = d4*4 + dd;
        float fd = dd==0?fq.x : dd==1?fq.y : dd==2?fq.z : fq.w;
        float4 wv = *(const float4*)&s1[d*64 + c4*4];
        a0=fmaf(fd,wv.x,a0); a1=fmaf(fd,wv.y,a1); a2=fmaf(fd,wv.z,a2); a3=fmaf(fd,wv.w,a3);
      }
    }
    o1[c4*4+0]=elu_f(a0); o1[c4*4+1]=elu_f(a1); o1[c4*4+2]=elu_f(a2); o1[c4*4+3]=elu_f(a3);
  }
  float o2[32];
  #pragma unroll 1
  for (int c4 = 0; c4 < 8; c4++){
    float a0=t2[c4*4+0], a1=t2[c4*4+1], a2=t2[c4*4+2], a3=t2[c4*4+3];
    #pragma unroll
    for (int d = 0; d < 64; d++){
      float fd = o1[d];
      float4 wv = *(const float4*)&s2[d*32 + c4*4];
      a0=fmaf(fd,wv.x,a0); a1=fmaf(fd,wv.y,a1); a2=fmaf(fd,wv.z,a2); a3=fmaf(fd,wv.w,a3);
    }
    o2[c4*4+0]=elu_f(a0); o2[c4*4+1]=elu_f(a1); o2[c4*4+2]=elu_f(a2); o2[c4*4+3]=elu_f(a3);
  }
  float4* op = (float4*)(out + (size_t)n*8);
  #pragma unroll
  for (int c4 = 0; c4 < 2; c4++){
    float a0=t3[c4*4+0], a1=t3[c4*4+1], a2=t3[c4*4+2], a3=t3[c4*4+3];
    #pragma unroll
    for (int d = 0; d < 32; d++){
      float fd = o2[d];
      float4 wv = *(const float4*)&s3[d*8 + c4*4];
      a0=fmaf(fd,wv.x,a0); a1=fmaf(fd,wv.y,a1); a2=fmaf(fd,wv.z,a2); a3=fmaf(fd,wv.w,a3);
    }
    float4 o; o.x=a0; o.y=a1; o.z=a2; o.w=a3;
    op[c4] = o;
  }
}

extern "C" void kernel_launch(void* const* d_in, const int* in_sizes, int n_in,
                              void* d_out, int out_size, void* d_ws, size_t ws_size,
                              hipStream_t stream){
  (void)n_in; (void)out_size;
  const float* x     = (const float*)d_in[0];
  const int*   ei    = (const int*)d_in[2];
  const int    E     = in_sizes[2] / 2;
  const float* encW1 = (const float*)d_in[3];
  const float* encb1 = (const float*)d_in[4];
  const float* encW2 = (const float*)d_in[5];
  const float* encb2 = (const float*)d_in[6];
  const float* convW = (const float*)d_in[7];
  const float* convb = (const float*)d_in[8];
  const float* bng   = (const float*)d_in[9];
  const float* bnb   = (const float*)d_in[10];
  const float* bnm   = (const float*)d_in[11];
  const float* bnv   = (const float*)d_in[12];
  const float* gatW  = (const float*)d_in[13];
  const float* gatas = (const float*)d_in[14];
  const float* gatad = (const float*)d_in[15];
  const float* gatb  = (const float*)d_in[16];
  const float* oW1   = (const float*)d_in[17];
  const float* ob1   = (const float*)d_in[18];
  const float* oW2   = (const float*)d_in[19];
  const float* ob2   = (const float*)d_in[20];
  const float* oW3   = (const float*)d_in[21];
  const float* ob3   = (const float*)d_in[22];

  char* wp = (char*)d_ws;
  auto alloc = [&](size_t bytes)->void*{
    void* p = (void*)wp; wp += (bytes + 255) & ~((size_t)255); return p;
  };
  float* fA     = (float*)alloc((size_t)NTOT*64*4);
  float* fB     = (float*)alloc((size_t)NTOT*64*4);
  float* ubuf   = (float*)alloc((size_t)NTOT*64*4);
  float* vbuf   = (float*)alloc((size_t)NTOT*64*4);
  float* sqb    = (float*)alloc((size_t)NTOT*4);
  int*   idxb   = (int*)  alloc((size_t)NTOT*KNN*4);
  float* xhb    = (float*)alloc((size_t)NTOT*256*4);
  float* alb    = (float*)alloc((size_t)NTOT*8*4);
  int*   degb   = (int*)  alloc((size_t)NTOT*4);
  int*   rowptr = (int*)  alloc((size_t)(NTOT+1)*4);
  int*   cursor = (int*)  alloc((size_t)NTOT*4);
  int*   csr    = (int*)  alloc((size_t)(E+NTOT)*4);

  size_t used = (size_t)(wp - (char*)d_ws);
  size_t distFull = (size_t)NB  * NPB * NPB * sizeof(float);  // ~302 MB
  size_t distOne  = (size_t)NPB * NPB * sizeof(float);        // ~37.8 MB
  int mode = (ws_size >= used + distFull) ? 2 : (ws_size >= used + distOne ? 1 : 0);
  float* Dbuf = (float*)wp;   // remaining workspace (mode>0)

  enc_kernel<<<96,256,0,stream>>>(x, encW1, encb1, encW2, encb2, fA);
  float* cur = fA; float* nxt = fB;
  for (int l = 0; l < 3; l++){
    sq_kernel<<<96,256,0,stream>>>(cur, sqb);
    if (mode == 2){
      dist_kernel  <<<dim3(24,24,8),256,0,stream>>>(cur, sqb, Dbuf);
      select_kernel<<<NTOT/4,       256,0,stream>>>(Dbuf, idxb, 0);
    } else if (mode == 1){
      for (int b = 0; b < NB; b++){
        dist_kernel  <<<dim3(24,24,1),256,0,stream>>>(cur + (size_t)b*NPB*HD, sqb + (size_t)b*NPB, Dbuf);
        select_kernel<<<NPB/4,        256,0,stream>>>(Dbuf, idxb, b*NPB);
      }
    } else {
      knn_kernel<<<384,256,0,stream>>>(cur, sqb, idxb);
    }
    uv_kernel  <<<96,  256,0,stream>>>(cur, convW + (size_t)l*8192, convb + l*64, ubuf, vbuf);
    pool_kernel<<<6144,256,0,stream>>>(ubuf, vbuf, idxb, cur,
                                       bng + l*64, bnb + l*64, bnm + l*64, bnv + l*64, nxt);
    float* tmp = cur; cur = nxt; nxt = tmp;
  }
  deg_init   <<<96,            256,0,stream>>>(degb);
  deg_hist   <<<(E+255)/256,   256,0,stream>>>(ei, E, degb);
  scan_kernel<<<1,             256,0,stream>>>(degb, rowptr, cursor);
  scatter_kernel<<<(E+NTOT+255)/256,256,0,stream>>>(ei, E, cursor, csr);
  for (int l = 0; l < 2; l++){
    xh_kernel <<<96,  256,0,stream>>>(cur, gatW + (size_t)l*16384, gatas + l*256, gatad + l*256, xhb, alb);
    agg_kernel<<<6144,256,0,stream>>>(xhb, alb, rowptr, csr, cur, gatb + l*64, nxt);
    float* tmp = cur; cur = nxt; nxt = tmp;
  }
  mlp_kernel<<<96,256,0,stream>>>(cur, oW1, ob1, oW2, ob2, oW3, ob3, (float*)d_out);
}

// Round 3
// 2322.088 us; speedup vs baseline: 2.4671x; 1.3174x over previous
//
#include <hip/hip_runtime.h>
#include <math.h>

// Problem constants (match reference)
#define NTOT  24576      // B*N nodes
#define NB    8
#define NPB   3072       // nodes per batch
#define HD    64
#define KNN   20

__device__ __forceinline__ float elu_f(float x){ return x > 0.f ? x : expm1f(x); }
__device__ __forceinline__ float lrelu_f(float x){ return x > 0.f ? x : 0.2f*x; }

// ---------------- encoder: x(NT,8) -> elu(elu(x@W1+b1)@W2+b2) (NT,64) ----------------
__global__ __launch_bounds__(256) void enc_kernel(const float* __restrict__ x,
    const float* __restrict__ W1, const float* __restrict__ b1,
    const float* __restrict__ W2, const float* __restrict__ b2,
    float* __restrict__ out){
  __shared__ float sW1[256], sb1[32], sW2[2048], sb2[64];
  int t = threadIdx.x;
  if (t < 256) sW1[t] = W1[t];
  for (int i = t; i < 2048; i += 256) sW2[i] = W2[i];
  if (t < 32) sb1[t] = b1[t];
  if (t < 64) sb2[t] = b2[t];
  __syncthreads();
  int n = blockIdx.x*256 + t;
  const float4* xp = (const float4*)(x + (size_t)n*8);
  float4 x0 = xp[0], x1 = xp[1];
  float xi[8] = {x0.x,x0.y,x0.z,x0.w,x1.x,x1.y,x1.z,x1.w};
  float h1[32];
  #pragma unroll
  for (int j = 0; j < 32; j++){
    float a = sb1[j];
    #pragma unroll
    for (int d = 0; d < 8; d++) a = fmaf(xi[d], sW1[d*32+j], a);
    h1[j] = elu_f(a);
  }
  float4* op = (float4*)(out + (size_t)n*64);
  #pragma unroll
  for (int c4 = 0; c4 < 16; c4++){
    float a0 = sb2[c4*4+0], a1 = sb2[c4*4+1], a2 = sb2[c4*4+2], a3 = sb2[c4*4+3];
    #pragma unroll
    for (int d = 0; d < 32; d++){
      float hd = h1[d];
      float4 wv = *(const float4*)&sW2[d*64 + c4*4];
      a0 = fmaf(hd, wv.x, a0); a1 = fmaf(hd, wv.y, a1);
      a2 = fmaf(hd, wv.z, a2); a3 = fmaf(hd, wv.w, a3);
    }
    float4 o; o.x=elu_f(a0); o.y=elu_f(a1); o.z=elu_f(a2); o.w=elu_f(a3);
    op[c4] = o;
  }
}

// ---------------- squared norms ----------------
__global__ __launch_bounds__(256) void sq_kernel(const float* __restrict__ f, float* __restrict__ sq){
  int n = blockIdx.x*256 + threadIdx.x;
  const float4* p = (const float4*)(f + (size_t)n*64);
  float s = 0.f;
  #pragma unroll
  for (int i = 0; i < 16; i++){
    float4 v = p[i];
    s = fmaf(v.x,v.x,s); s = fmaf(v.y,v.y,s); s = fmaf(v.z,v.z,s); s = fmaf(v.w,v.w,s);
  }
  sq[n] = s;
}

// ---------------- distance GEMM: s[q][m] = sq[m] - 2*dot(q,m), 128x128 tiles ----------------
// grid = dim3(24, cq/128, NB), 256 threads, 8x8 micro-tile per thread.
// D layout: [b][qc][m] with qc in [0,cq) (chunk-local), m in [0,NPB).
__global__ __launch_bounds__(256) void dist_kernel(const float* __restrict__ feat,
    const float* __restrict__ sqn, float* __restrict__ D, int q0, int cq){
  int b  = blockIdx.z;
  int m0 = blockIdx.x * 128;
  int qc0 = blockIdx.y * 128;          // chunk-local query tile base
  int qg0 = q0 + qc0;                  // within-batch query base
  const float* fb = feat + (size_t)b*NPB*HD;
  float* Db = D + (size_t)b*cq*NPB;
  __shared__ float As[64][128];   // [dim][query]
  __shared__ float Bs[64][128];   // [dim][cand]
  int t = threadIdx.x;
  {
    int r = t >> 1, dc = (t & 1) * 32;
    const float4* pa = (const float4*)(fb + (size_t)(qg0 + r)*HD + dc);
    const float4* pb = (const float4*)(fb + (size_t)(m0 + r)*HD + dc);
    #pragma unroll
    for (int i = 0; i < 8; i++){
      float4 va = pa[i], vb = pb[i];
      int d = dc + i*4;
      As[d][r]=va.x; As[d+1][r]=va.y; As[d+2][r]=va.z; As[d+3][r]=va.w;
      Bs[d][r]=vb.x; Bs[d+1][r]=vb.y; Bs[d+2][r]=vb.z; Bs[d+3][r]=vb.w;
    }
  }
  __syncthreads();
  int tx = t & 15, ty = t >> 4;
  float acc[8][8];
  #pragma unroll
  for (int i = 0; i < 8; i++)
    #pragma unroll
    for (int j = 0; j < 8; j++) acc[i][j] = 0.f;
  #pragma unroll 2
  for (int d = 0; d < 64; d++){
    float af[8], bf[8];
    *(float4*)&af[0] = *(const float4*)&As[d][ty*8];
    *(float4*)&af[4] = *(const float4*)&As[d][ty*8+4];
    *(float4*)&bf[0] = *(const float4*)&Bs[d][tx*8];
    *(float4*)&bf[4] = *(const float4*)&Bs[d][tx*8+4];
    #pragma unroll
    for (int i = 0; i < 8; i++)
      #pragma unroll
      for (int j = 0; j < 8; j++)
        acc[i][j] = fmaf(af[i], bf[j], acc[i][j]);
  }
  const float4* sp = (const float4*)(sqn + (size_t)b*NPB + m0 + tx*8);
  float4 sq0 = sp[0], sq1 = sp[1];
  float sqv[8] = {sq0.x,sq0.y,sq0.z,sq0.w,sq1.x,sq1.y,sq1.z,sq1.w};
  #pragma unroll
  for (int i = 0; i < 8; i++){
    float* orow = Db + (size_t)(qc0 + ty*8 + i)*NPB + m0 + tx*8;
    float4 o0, o1;
    o0.x = fmaf(-2.f, acc[i][0], sqv[0]); o0.y = fmaf(-2.f, acc[i][1], sqv[1]);
    o0.z = fmaf(-2.f, acc[i][2], sqv[2]); o0.w = fmaf(-2.f, acc[i][3], sqv[3]);
    o1.x = fmaf(-2.f, acc[i][4], sqv[4]); o1.y = fmaf(-2.f, acc[i][5], sqv[5]);
    o1.z = fmaf(-2.f, acc[i][6], sqv[6]); o1.w = fmaf(-2.f, acc[i][7], sqv[7]);
    *(float4*)orow = o0; *((float4*)orow + 1) = o1;
  }
}

// ---------------- top-20 select: one wave per query row ----------------
// Each lane owns candidates m = lane*4 + c*256 + e (12 float4 loads), keeps a
// private sorted top-20, then 20 rounds of lex-min (d, idx) wave reduction.
__global__ __launch_bounds__(256) void select_kernel(const float* __restrict__ D,
    int* __restrict__ idxout, int q0, int cq){
  int w = blockIdx.x*4 + (int)(threadIdx.x >> 6);   // row in [0, NB*cq)
  int lane = threadIdx.x & 63;
  int b  = w / cq;
  int qc = w - b*cq;
  int ql = q0 + qc;                  // within-batch query index
  int g  = b*NPB + ql;               // global query node id
  const float* row = D + ((size_t)b*cq + qc) * NPB;
  float dl[KNN]; int il[KNN];
  #pragma unroll
  for (int k = 0; k < KNN; k++){ dl[k] = 3.4e38f; il[k] = 0x7fffffff; }
  #pragma unroll 1
  for (int c = 0; c < 12; c++){
    int mbase = c*256 + lane*4;
    float4 v = *(const float4*)(row + mbase);
    #pragma unroll
    for (int e = 0; e < 4; e++){
      int m = mbase + e;
      float s = (e==0)?v.x:(e==1)?v.y:(e==2)?v.z:v.w;
      if (m == ql) continue;                    // diagonal
      if (s < dl[KNN-1]){                       // stable sorted insert
        #pragma unroll
        for (int k = KNN-1; k >= 1; k--){
          bool c1 = s < dl[k-1];
          bool c0 = s < dl[k];
          dl[k] = c1 ? dl[k-1] : (c0 ? s : dl[k]);
          il[k] = c1 ? il[k-1] : (c0 ? m : il[k]);
        }
        if (s < dl[0]){ dl[0] = s; il[0] = m; }
      }
    }
  }
  int res = 0;
  #pragma unroll 1
  for (int r = 0; r < KNN; r++){
    float d = dl[0]; int i = il[0];
    #pragma unroll
    for (int off = 1; off < 64; off <<= 1){
      float od = __shfl_xor(d, off, 64);
      int   oi = __shfl_xor(i, off, 64);
      if (od < d || (od == d && oi < i)){ d = od; i = oi; }
    }
    if (lane == r) res = i;
    if (il[0] == i){                 // winner lane pops its head (i unique per lane)
      #pragma unroll
      for (int k = 0; k < KNN-1; k++){ dl[k] = dl[k+1]; il[k] = il[k+1]; }
      dl[KNN-1] = 3.4e38f; il[KNN-1] = 0x7fffffff;
    }
  }
  if (lane < KNN) idxout[(size_t)g*KNN + lane] = b*NPB + res;
}

// ---------------- legacy fused kNN (fallback when workspace too small) ----------------
__global__ __launch_bounds__(256) void knn_kernel(const float* __restrict__ feat,
    const float* __restrict__ sqn, int* __restrict__ idxout){
  int b  = blockIdx.x / 48;
  int q0 = (blockIdx.x % 48) * 64;
  int t  = threadIdx.x;
  int ty = t >> 4, tx = t & 15;
  __shared__ float As[64][64];
  __shared__ float Bs[64][64];
  __shared__ float Ds[64][68];
  __shared__ float ssq[64];
  const float* fb = feat + (size_t)b*NPB*HD;
  {
    int r = t >> 2, dc = (t & 3)*16;
    const float4* src = (const float4*)(fb + (size_t)(q0 + r)*HD + dc);
    #pragma unroll
    for (int i = 0; i < 4; i++){
      float4 v = src[i]; int d = dc + i*4;
      As[d][r]=v.x; As[d+1][r]=v.y; As[d+2][r]=v.z; As[d+3][r]=v.w;
    }
  }
  float dist[KNN]; int didx[KNN];
  #pragma unroll
  for (int i = 0; i < KNN; i++){ dist[i] = 3.4e38f; didx[i] = 0; }
  int qloc = q0 + t;
  for (int m0 = 0; m0 < NPB; m0 += 64){
    __syncthreads();
    {
      int r = t >> 2, dc = (t & 3)*16;
      const float4* src = (const float4*)(fb + (size_t)(m0 + r)*HD + dc);
      #pragma unroll
      for (int i = 0; i < 4; i++){
        float4 v = src[i]; int d = dc + i*4;
        Bs[d][r]=v.x; Bs[d+1][r]=v.y; Bs[d+2][r]=v.z; Bs[d+3][r]=v.w;
      }
      if (t < 64) ssq[t] = sqn[(size_t)b*NPB + m0 + t];
    }
    __syncthreads();
    float acc[4][4];
    #pragma unroll
    for (int i = 0; i < 4; i++)
      #pragma unroll
      for (int j = 0; j < 4; j++) acc[i][j] = 0.f;
    #pragma unroll 4
    for (int d = 0; d < 64; d++){
      float4 av = *(const float4*)&As[d][ty*4];
      float4 bv = *(const float4*)&Bs[d][tx*4];
      acc[0][0]=fmaf(av.x,bv.x,acc[0][0]); acc[0][1]=fmaf(av.x,bv.y,acc[0][1]);
      acc[0][2]=fmaf(av.x,bv.z,acc[0][2]); acc[0][3]=fmaf(av.x,bv.w,acc[0][3]);
      acc[1][0]=fmaf(av.y,bv.x,acc[1][0]); acc[1][1]=fmaf(av.y,bv.y,acc[1][1]);
      acc[1][2]=fmaf(av.y,bv.z,acc[1][2]); acc[1][3]=fmaf(av.y,bv.w,acc[1][3]);
      acc[2][0]=fmaf(av.z,bv.x,acc[2][0]); acc[2][1]=fmaf(av.z,bv.y,acc[2][1]);
      acc[2][2]=fmaf(av.z,bv.z,acc[2][2]); acc[2][3]=fmaf(av.z,bv.w,acc[2][3]);
      acc[3][0]=fmaf(av.w,bv.x,acc[3][0]); acc[3][1]=fmaf(av.w,bv.y,acc[3][1]);
      acc[3][2]=fmaf(av.w,bv.z,acc[3][2]); acc[3][3]=fmaf(av.w,bv.w,acc[3][3]);
    }
    #pragma unroll
    for (int i = 0; i < 4; i++){
      float4 o; o.x=acc[i][0]; o.y=acc[i][1]; o.z=acc[i][2]; o.w=acc[i][3];
      *(float4*)&Ds[ty*4+i][tx*4] = o;
    }
    __syncthreads();
    if (t < 64){
      #pragma unroll 1
      for (int j = 0; j < 64; j++){
        int m = m0 + j;
        float s = fmaf(-2.f, Ds[t][j], ssq[j]);
        if (m == qloc) continue;
        if (s < dist[KNN-1]){
          #pragma unroll
          for (int k = KNN-1; k >= 1; k--){
            bool sh = s < dist[k-1];
            float nd = sh ? dist[k-1] : (s < dist[k] ? s : dist[k]);
            int   ni = sh ? didx[k-1] : (s < dist[k] ? m : didx[k]);
            dist[k] = nd; didx[k] = ni;
          }
          if (s < dist[0]){ dist[0] = s; didx[0] = m; }
        }
      }
    }
  }
  if (t < 64){
    int* op = idxout + (size_t)((size_t)b*NPB + q0 + t)*KNN;
    #pragma unroll
    for (int k = 0; k < KNN; k++) op[k] = b*NPB + didx[k];
  }
}

// ---------------- edge-conv factorization: u = x@(Wt-Wb)+b, v = x@Wb ----------------
__global__ __launch_bounds__(256) void uv_kernel(const float* __restrict__ feat,
    const float* __restrict__ W, const float* __restrict__ cb,
    float* __restrict__ u, float* __restrict__ v){
  __shared__ float sW[128*64];
  int t = threadIdx.x;
  for (int i = t; i < 8192; i += 256) sW[i] = W[i];
  __syncthreads();
  int n = blockIdx.x*256 + t;
  float4 fv[16];
  const float4* fp = (const float4*)(feat + (size_t)n*64);
  #pragma unroll
  for (int i = 0; i < 16; i++) fv[i] = fp[i];
  float4* up = (float4*)(u + (size_t)n*64);
  float4* vp = (float4*)(v + (size_t)n*64);
  #pragma unroll 1
  for (int c4 = 0; c4 < 16; c4++){
    float ua0=0,ua1=0,ua2=0,ua3=0, vb0=0,vb1=0,vb2=0,vb3=0;
    #pragma unroll
    for (int d4 = 0; d4 < 16; d4++){
      float4 fq = fv[d4];
      #pragma unroll
      for (int dd = 0; dd < 4; dd++){
        int d = d4*4 + dd;
        float fd = dd==0?fq.x : dd==1?fq.y : dd==2?fq.z : fq.w;
        float4 wt = *(const float4*)&sW[d*64 + c4*4];
        float4 wb = *(const float4*)&sW[(64+d)*64 + c4*4];
        ua0=fmaf(fd,wt.x,ua0); ua1=fmaf(fd,wt.y,ua1); ua2=fmaf(fd,wt.z,ua2); ua3=fmaf(fd,wt.w,ua3);
        vb0=fmaf(fd,wb.x,vb0); vb1=fmaf(fd,wb.y,vb1); vb2=fmaf(fd,wb.z,vb2); vb3=fmaf(fd,wb.w,vb3);
      }
    }
    float4 cbv = *(const float4*)&cb[c4*4];
    float4 uo, vo;
    uo.x = cbv.x + ua0 - vb0; uo.y = cbv.y + ua1 - vb1;
    uo.z = cbv.z + ua2 - vb2; uo.w = cbv.w + ua3 - vb3;
    vo.x = vb0; vo.y = vb1; vo.z = vb2; vo.w = vb3;
    up[c4] = uo; vp[c4] = vo;
  }
}

// ---------------- max-pool over k neighbors + BN + residual (one wave per node) ----------------
__global__ __launch_bounds__(256) void pool_kernel(const float* __restrict__ u, const float* __restrict__ v,
    const int* __restrict__ idx, const float* __restrict__ resid,
    const float* __restrict__ bg, const float* __restrict__ bb,
    const float* __restrict__ bm, const float* __restrict__ bv,
    float* __restrict__ out){
  int gid = blockIdx.x*256 + threadIdx.x;
  int n = gid >> 6, lane = gid & 63;
  float uc = u[(size_t)n*64 + lane];
  float scale = bg[lane] / sqrtf(bv[lane] + 1e-5f);
  float bias  = bb[lane] - bm[lane]*scale;
  const int* ip = idx + (size_t)n*KNN;
  float acc = -3.4e38f;
  #pragma unroll 4
  for (int k = 0; k < KNN; k++){
    int j = ip[k];
    float s = uc + v[(size_t)j*64 + lane];
    acc = fmaxf(acc, fmaf(elu_f(s), scale, bias));
  }
  out[(size_t)n*64 + lane] = acc + resid[(size_t)n*64 + lane];
}

// ---------------- CSR build over dst (edges + self loops) ----------------
__global__ void deg_init(int* deg){ int i = blockIdx.x*256 + threadIdx.x; if (i < NTOT) deg[i] = 1; }
__global__ void deg_hist(const int* __restrict__ ei, int E, int* deg){
  int i = blockIdx.x*256 + threadIdx.x; if (i < E) atomicAdd(&deg[ei[E + i]], 1);
}
__global__ void scan_kernel(const int* __restrict__ deg, int* __restrict__ rowptr, int* __restrict__ cursor){
  __shared__ int part[256];
  int t = threadIdx.x;
  int base = t*96;
  int s = 0;
  for (int i = 0; i < 96; i++) s += deg[base + i];
  part[t] = s;
  __syncthreads();
  for (int off = 1; off < 256; off <<= 1){
    int xv = (t >= off) ? part[t - off] : 0;
    __syncthreads();
    part[t] += xv;
    __syncthreads();
  }
  int run = part[t] - s;
  for (int i = 0; i < 96; i++){
    rowptr[base + i] = run; cursor[base + i] = run; run += deg[base + i];
  }
  if (t == 255) rowptr[NTOT] = run;
}
__global__ void scatter_kernel(const int* __restrict__ ei, int E, int* cursor, int* __restrict__ csr){
  int i = blockIdx.x*256 + threadIdx.x;
  if (i >= E + NTOT) return;
  int s, d;
  if (i < E){ s = ei[i]; d = ei[E + i]; } else { s = i - E; d = s; }
  int pos = atomicAdd(&cursor[d], 1);
  csr[pos] = s;
}

// ---------------- GAT: xh = x@W (NT,256), al_s/al_d per head ----------------
__global__ __launch_bounds__(256) void xh_kernel(const float* __restrict__ feat,
    const float* __restrict__ W, const float* __restrict__ asrc, const float* __restrict__ adst,
    float* __restrict__ xh, float* __restrict__ al){
  __shared__ float sW[64*128];
  __shared__ float sas[256], sad[256];
  int t = threadIdx.x;
  if (t < 256){ sas[t] = asrc[t]; sad[t] = adst[t]; }
  int n = blockIdx.x*256 + t;
  float4 fv[16];
  const float4* fp = (const float4*)(feat + (size_t)n*64);
  #pragma unroll
  for (int i = 0; i < 16; i++) fv[i] = fp[i];
  float4* xp = (float4*)(xh + (size_t)n*256);
  float* ap = al + (size_t)n*8;
  #pragma unroll 1
  for (int half = 0; half < 2; half++){
    __syncthreads();
    for (int i = t; i < 8192; i += 256){
      int d = i >> 7, c = i & 127;
      sW[i] = W[d*256 + half*128 + c];
    }
    __syncthreads();
    #pragma unroll 1
    for (int hh = 0; hh < 2; hh++){
      int h = half*2 + hh;
      float as_ = 0.f, ad_ = 0.f;
      #pragma unroll 1
      for (int cc = 0; cc < 64; cc += 4){
        int c  = h*64 + cc;
        int cl = hh*64 + cc;
        float a0=0,a1=0,a2=0,a3=0;
        #pragma unroll
        for (int d4 = 0; d4 < 16; d4++){
          float4 fq = fv[d4];
          #pragma unroll
          for (int dd = 0; dd < 4; dd++){
            int d = d4*4 + dd;
            float fd = dd==0?fq.x : dd==1?fq.y : dd==2?fq.z : fq.w;
            float4 wv = *(const float4*)&sW[d*128 + cl];
            a0=fmaf(fd,wv.x,a0); a1=fmaf(fd,wv.y,a1); a2=fmaf(fd,wv.z,a2); a3=fmaf(fd,wv.w,a3);
          }
        }
        float4 o; o.x=a0; o.y=a1; o.z=a2; o.w=a3;
        xp[c >> 2] = o;
        as_ = fmaf(a0, sas[c], fmaf(a1, sas[c+1], fmaf(a2, sas[c+2], fmaf(a3, sas[c+3], as_))));
        ad_ = fmaf(a0, sad[c], fmaf(a1, sad[c+1], fmaf(a2, sad[c+2], fmaf(a3, sad[c+3], ad_))));
      }
      ap[h] = as_; ap[4 + h] = ad_;
    }
  }
}

// ---------------- GAT aggregation: one-pass online softmax, one wave per dst ----------------
__global__ __launch_bounds__(256) void agg_kernel(const float* __restrict__ xh, const float* __restrict__ al,
    const int* __restrict__ rowptr, const int* __restrict__ csr,
    const float* __restrict__ resid, const float* __restrict__ bias,
    float* __restrict__ out){
  int gid = blockIdx.x*256 + threadIdx.x;
  int n = gid >> 6, lane = gid & 63;
  int rs = rowptr[n], re = rowptr[n+1];
  int h = lane >> 4, coff = (lane & 15)*4;
  float ald_h = al[(size_t)n*8 + 4 + h];
  float mx = -3.4e38f, den = 0.f;
  float ax=0.f, ay=0.f, az=0.f, aw=0.f;
  #pragma unroll 2
  for (int e = rs; e < re; e++){
    int s = csr[e];
    float a = al[(size_t)s*8 + h] + ald_h;
    a = a > 0.f ? a : 0.2f*a;                   // leaky_relu
    float nm = fmaxf(mx, a);
    float corr = __expf(mx - nm);               // 1 when max unchanged, 0 on first iter
    float ea   = __expf(a - nm);
    mx = nm;
    float4 xv = *(const float4*)(xh + (size_t)s*256 + h*64 + coff);
    den = fmaf(den, corr, ea);
    ax = fmaf(ax, corr, ea*xv.x); ay = fmaf(ay, corr, ea*xv.y);
    az = fmaf(az, corr, ea*xv.z); aw = fmaf(aw, corr, ea*xv.w);
  }
  float rinv = 1.f / (den + 1e-16f);
  float r0 = ax*rinv, r1 = ay*rinv, r2 = az*rinv, r3 = aw*rinv;
  r0 += __shfl_xor(r0, 16, 64); r1 += __shfl_xor(r1, 16, 64);
  r2 += __shfl_xor(r2, 16, 64); r3 += __shfl_xor(r3, 16, 64);
  r0 += __shfl_xor(r0, 32, 64); r1 += __shfl_xor(r1, 32, 64);
  r2 += __shfl_xor(r2, 32, 64); r3 += __shfl_xor(r3, 32, 64);
  if (lane < 16){
    float4 bs = *(const float4*)(bias + coff);
    float4 rv = *(const float4*)(resid + (size_t)n*64 + coff);
    float4 o;
    o.x = r0*0.25f + bs.x + rv.x; o.y = r1*0.25f + bs.y + rv.y;
    o.z = r2*0.25f + bs.z + rv.z; o.w = r3*0.25f + bs.w + rv.w;
    *(float4*)(out + (size_t)n*64 + coff) = o;
  }
}

// ---------------- output MLP: 64->64 elu ->32 elu ->8 ----------------
__global__ __launch_bounds__(256) void mlp_kernel(const float* __restrict__ feat,
    const float* __restrict__ W1, const float* __restrict__ b1,
    const float* __restrict__ W2, const float* __restrict__ b2,
    const float* __restrict__ W3, const float* __restrict__ b3,
    float* __restrict__ out){
  __shared__ float s1[4096], s2[2048], s3[256], t1[64], t2[32], t3[8];
  int t = threadIdx.x;
  for (int i = t; i < 4096; i += 256) s1[i] = W1[i];
  for (int i = t; i < 2048; i += 256) s2[i] = W2[i];
  if (t < 256) s3[t] = W3[t];
  if (t < 64) t1[t] = b1[t];
  if (t < 32) t2[t] = b2[t];
  if (t < 8)  t3[t] = b3[t];
  __syncthreads();
  int n = blockIdx.x*256 + t;
  float4 fv[16];
  const float4* fp = (const float4*)(feat + (size_t)n*64);
  #pragma unroll
  for (int i = 0; i < 16; i++) fv[i] = fp[i];
  float o1[64];
  #pragma unroll 1
  for (int c4 = 0; c4 < 16; c4++){
    float a0=t1[c4*4+0], a1=t1[c4*4+1], a2=t1[c4*4+2], a3=t1[c4*4+3];
    #pragma unroll
    for (int d4 = 0; d4 < 16; d4++){
      float4 fq = fv[d4];
      #pragma unroll
      for (int dd = 0; dd < 4; dd++){
        int d = d4*4 + dd;
        float fd = dd==0?fq.x : dd==1?fq.y : dd==2?fq.z : fq.w;
        float4 wv = *(const float4*)&s1[d*64 + c4*4];
        a0=fmaf(fd,wv.x,a0); a1=fmaf(fd,wv.y,a1); a2=fmaf(fd,wv.z,a2); a3=fmaf(fd,wv.w,a3);
      }
    }
    o1[c4*4+0]=elu_f(a0); o1[c4*4+1]=elu_f(a1); o1[c4*4+2]=elu_f(a2); o1[c4*4+3]=elu_f(a3);
  }
  float o2[32];
  #pragma unroll 1
  for (int c4 = 0; c4 < 8; c4++){
    float a0=t2[c4*4+0], a1=t2[c4*4+1], a2=t2[c4*4+2], a3=t2[c4*4+3];
    #pragma unroll
    for (int d = 0; d < 64; d++){
      float fd = o1[d];
      float4 wv = *(const float4*)&s2[d*32 + c4*4];
      a0=fmaf(fd,wv.x,a0); a1=fmaf(fd,wv.y,a1); a2=fmaf(fd,wv.z,a2); a3=fmaf(fd,wv.w,a3);
    }
    o2[c4*4+0]=elu_f(a0); o2[c4*4+1]=elu_f(a1); o2[c4*4+2]=elu_f(a2); o2[c4*4+3]=elu_f(a3);
  }
  float4* op = (float4*)(out + (size_t)n*8);
  #pragma unroll
  for (int c4 = 0; c4 < 2; c4++){
    float a0=t3[c4*4+0], a1=t3[c4*4+1], a2=t3[c4*4+2], a3=t3[c4*4+3];
    #pragma unroll
    for (int d = 0; d < 32; d++){
      float fd = o2[d];
      float4 wv = *(const float4*)&s3[d*8 + c4*4];
      a0=fmaf(fd,wv.x,a0); a1=fmaf(fd,wv.y,a1); a2=fmaf(fd,wv.z,a2); a3=fmaf(fd,wv.w,a3);
    }
    float4 o; o.x=a0; o.y=a1; o.z=a2; o.w=a3;
    op[c4] = o;
  }
}

extern "C" void kernel_launch(void* const* d_in, const int* in_sizes, int n_in,
                              void* d_out, int out_size, void* d_ws, size_t ws_size,
                              hipStream_t stream){
  (void)n_in; (void)out_size;
  const float* x     = (const float*)d_in[0];
  const int*   ei    = (const int*)d_in[2];
  const int    E     = in_sizes[2] / 2;
  const float* encW1 = (const float*)d_in[3];
  const float* encb1 = (const float*)d_in[4];
  const float* encW2 = (const float*)d_in[5];
  const float* encb2 = (const float*)d_in[6];
  const float* convW = (const float*)d_in[7];
  const float* convb = (const float*)d_in[8];
  const float* bng   = (const float*)d_in[9];
  const float* bnb   = (const float*)d_in[10];
  const float* bnm   = (const float*)d_in[11];
  const float* bnv   = (const float*)d_in[12];
  const float* gatW  = (const float*)d_in[13];
  const float* gatas = (const float*)d_in[14];
  const float* gatad = (const float*)d_in[15];
  const float* gatb  = (const float*)d_in[16];
  const float* oW1   = (const float*)d_in[17];
  const float* ob1   = (const float*)d_in[18];
  const float* oW2   = (const float*)d_in[19];
  const float* ob2   = (const float*)d_in[20];
  const float* oW3   = (const float*)d_in[21];
  const float* ob3   = (const float*)d_in[22];

  char* wp = (char*)d_ws;
  auto alloc = [&](size_t bytes)->void*{
    void* p = (void*)wp; wp += (bytes + 255) & ~((size_t)255); return p;
  };
  float* fA     = (float*)alloc((size_t)NTOT*64*4);
  float* fB     = (float*)alloc((size_t)NTOT*64*4);
  float* ubuf   = (float*)alloc((size_t)NTOT*64*4);
  float* vbuf   = (float*)alloc((size_t)NTOT*64*4);
  float* sqb    = (float*)alloc((size_t)NTOT*4);
  int*   idxb   = (int*)  alloc((size_t)NTOT*KNN*4);
  float* xhb    = (float*)alloc((size_t)NTOT*256*4);
  float* alb    = (float*)alloc((size_t)NTOT*8*4);
  int*   degb   = (int*)  alloc((size_t)NTOT*4);
  int*   rowptr = (int*)  alloc((size_t)(NTOT+1)*4);
  int*   cursor = (int*)  alloc((size_t)NTOT*4);
  int*   csr    = (int*)  alloc((size_t)(E+NTOT)*4);

  size_t used  = (size_t)(wp - (char*)d_ws);
  size_t avail = ws_size > used ? ws_size - used : 0;
  // Query-chunk size (multiple of 128) so D[b][CQ][NPB] fits remaining ws.
  int CQ = (int)(avail / ((size_t)NB * NPB * sizeof(float)));
  CQ = (CQ / 128) * 128;
  if (CQ > NPB) CQ = NPB;
  float* Dbuf = (float*)wp;

  enc_kernel<<<96,256,0,stream>>>(x, encW1, encb1, encW2, encb2, fA);
  float* cur = fA; float* nxt = fB;
  for (int l = 0; l < 3; l++){
    sq_kernel<<<96,256,0,stream>>>(cur, sqb);
    if (CQ >= 128){
      for (int q0 = 0; q0 < NPB; q0 += CQ){
        int cq = NPB - q0 < CQ ? NPB - q0 : CQ;
        dist_kernel  <<<dim3(24, cq/128, NB),256,0,stream>>>(cur, sqb, Dbuf, q0, cq);
        select_kernel<<<(NB*cq)/4,           256,0,stream>>>(Dbuf, idxb, q0, cq);
      }
    } else {
      knn_kernel<<<384,256,0,stream>>>(cur, sqb, idxb);
    }
    uv_kernel  <<<96,  256,0,stream>>>(cur, convW + (size_t)l*8192, convb + l*64, ubuf, vbuf);
    pool_kernel<<<6144,256,0,stream>>>(ubuf, vbuf, idxb, cur,
                                       bng + l*64, bnb + l*64, bnm + l*64, bnv + l*64, nxt);
    float* tmp = cur; cur = nxt; nxt = tmp;
  }
  deg_init   <<<96,            256,0,stream>>>(degb);
  deg_hist   <<<(E+255)/256,   256,0,stream>>>(ei, E, degb);
  scan_kernel<<<1,             256,0,stream>>>(degb, rowptr, cursor);
  scatter_kernel<<<(E+NTOT+255)/256,256,0,stream>>>(ei, E, cursor, csr);
  for (int l = 0; l < 2; l++){
    xh_kernel <<<96,  256,0,stream>>>(cur, gatW + (size_t)l*16384, gatas + l*256, gatad + l*256, xhb, alb);
    agg_kernel<<<6144,256,0,stream>>>(xhb, alb, rowptr, csr, cur, gatb + l*64, nxt);
    float* tmp = cur; cur = nxt; nxt = tmp;
  }
  mlp_kernel<<<96,256,0,stream>>>(cur, oW1, ob1, oW2, ob2, oW3, ob3, (float*)d_out);
}

// Round 4
// 1778.441 us; speedup vs baseline: 3.2212x; 1.3057x over previous
//
#include <hip/hip_runtime.h>
#include <math.h>

// Problem constants (match reference)
#define NTOT  24576      // B*N nodes
#define NB    8
#define NPB   3072       // nodes per batch
#define HD    64
#define KNN   20

__device__ __forceinline__ float elu_f(float x){ return x > 0.f ? x : expm1f(x); }

// ---------------- encoder: x(NT,8) -> elu(elu(x@W1+b1)@W2+b2) (NT,64) ----------------
__global__ __launch_bounds__(256) void enc_kernel(const float* __restrict__ x,
    const float* __restrict__ W1, const float* __restrict__ b1,
    const float* __restrict__ W2, const float* __restrict__ b2,
    float* __restrict__ out){
  __shared__ float sW1[256], sb1[32], sW2[2048], sb2[64];
  int t = threadIdx.x;
  if (t < 256) sW1[t] = W1[t];
  for (int i = t; i < 2048; i += 256) sW2[i] = W2[i];
  if (t < 32) sb1[t] = b1[t];
  if (t < 64) sb2[t] = b2[t];
  __syncthreads();
  int n = blockIdx.x*256 + t;
  const float4* xp = (const float4*)(x + (size_t)n*8);
  float4 x0 = xp[0], x1 = xp[1];
  float xi[8] = {x0.x,x0.y,x0.z,x0.w,x1.x,x1.y,x1.z,x1.w};
  float h1[32];
  #pragma unroll
  for (int j = 0; j < 32; j++){
    float a = sb1[j];
    #pragma unroll
    for (int d = 0; d < 8; d++) a = fmaf(xi[d], sW1[d*32+j], a);
    h1[j] = elu_f(a);
  }
  float4* op = (float4*)(out + (size_t)n*64);
  #pragma unroll
  for (int c4 = 0; c4 < 16; c4++){
    float a0 = sb2[c4*4+0], a1 = sb2[c4*4+1], a2 = sb2[c4*4+2], a3 = sb2[c4*4+3];
    #pragma unroll
    for (int d = 0; d < 32; d++){
      float hd = h1[d];
      float4 wv = *(const float4*)&sW2[d*64 + c4*4];
      a0 = fmaf(hd, wv.x, a0); a1 = fmaf(hd, wv.y, a1);
      a2 = fmaf(hd, wv.z, a2); a3 = fmaf(hd, wv.w, a3);
    }
    float4 o; o.x=elu_f(a0); o.y=elu_f(a1); o.z=elu_f(a2); o.w=elu_f(a3);
    op[c4] = o;
  }
}

// ---------------- squared norms ----------------
__global__ __launch_bounds__(256) void sq_kernel(const float* __restrict__ f, float* __restrict__ sq){
  int n = blockIdx.x*256 + threadIdx.x;
  const float4* p = (const float4*)(f + (size_t)n*64);
  float s = 0.f;
  #pragma unroll
  for (int i = 0; i < 16; i++){
    float4 v = p[i];
    s = fmaf(v.x,v.x,s); s = fmaf(v.y,v.y,s); s = fmaf(v.z,v.z,s); s = fmaf(v.w,v.w,s);
  }
  sq[n] = s;
}

// ---------------- distance GEMM: s[q][m] = sq[m] - 2*dot(q,m), 128x128 tiles ----------------
__global__ __launch_bounds__(256) void dist_kernel(const float* __restrict__ feat,
    const float* __restrict__ sqn, float* __restrict__ D, int q0, int cq){
  int b  = blockIdx.z;
  int m0 = blockIdx.x * 128;
  int qc0 = blockIdx.y * 128;
  int qg0 = q0 + qc0;
  const float* fb = feat + (size_t)b*NPB*HD;
  float* Db = D + (size_t)b*cq*NPB;
  __shared__ float As[64][128];
  __shared__ float Bs[64][128];
  int t = threadIdx.x;
  {
    int r = t >> 1, dc = (t & 1) * 32;
    const float4* pa = (const float4*)(fb + (size_t)(qg0 + r)*HD + dc);
    const float4* pb = (const float4*)(fb + (size_t)(m0 + r)*HD + dc);
    #pragma unroll
    for (int i = 0; i < 8; i++){
      float4 va = pa[i], vb = pb[i];
      int d = dc + i*4;
      As[d][r]=va.x; As[d+1][r]=va.y; As[d+2][r]=va.z; As[d+3][r]=va.w;
      Bs[d][r]=vb.x; Bs[d+1][r]=vb.y; Bs[d+2][r]=vb.z; Bs[d+3][r]=vb.w;
    }
  }
  __syncthreads();
  int tx = t & 15, ty = t >> 4;
  float acc[8][8];
  #pragma unroll
  for (int i = 0; i < 8; i++)
    #pragma unroll
    for (int j = 0; j < 8; j++) acc[i][j] = 0.f;
  #pragma unroll 2
  for (int d = 0; d < 64; d++){
    float af[8], bf[8];
    *(float4*)&af[0] = *(const float4*)&As[d][ty*8];
    *(float4*)&af[4] = *(const float4*)&As[d][ty*8+4];
    *(float4*)&bf[0] = *(const float4*)&Bs[d][tx*8];
    *(float4*)&bf[4] = *(const float4*)&Bs[d][tx*8+4];
    #pragma unroll
    for (int i = 0; i < 8; i++)
      #pragma unroll
      for (int j = 0; j < 8; j++)
        acc[i][j] = fmaf(af[i], bf[j], acc[i][j]);
  }
  const float4* sp = (const float4*)(sqn + (size_t)b*NPB + m0 + tx*8);
  float4 sq0 = sp[0], sq1 = sp[1];
  float sqv[8] = {sq0.x,sq0.y,sq0.z,sq0.w,sq1.x,sq1.y,sq1.z,sq1.w};
  #pragma unroll
  for (int i = 0; i < 8; i++){
    float* orow = Db + (size_t)(qc0 + ty*8 + i)*NPB + m0 + tx*8;
    float4 o0, o1;
    o0.x = fmaf(-2.f, acc[i][0], sqv[0]); o0.y = fmaf(-2.f, acc[i][1], sqv[1]);
    o0.z = fmaf(-2.f, acc[i][2], sqv[2]); o0.w = fmaf(-2.f, acc[i][3], sqv[3]);
    o1.x = fmaf(-2.f, acc[i][4], sqv[4]); o1.y = fmaf(-2.f, acc[i][5], sqv[5]);
    o1.z = fmaf(-2.f, acc[i][6], sqv[6]); o1.w = fmaf(-2.f, acc[i][7], sqv[7]);
    *(float4*)orow = o0; *((float4*)orow + 1) = o1;
  }
}

// ---------------- top-20 select: two-phase exact threshold + bitonic ----------------
// One wave per query row. Phase 1: per-lane top-2 (values in regs). Phase 2:
// T = ~20th smallest of the 128 lane-top-2 (>= true v20, subset order stat).
// Phase 3: ballot-compact values <= T (superset of true top-20) into LDS.
// Phase 4: 64-lane bitonic on (key<<32|idx) -> exact lex top-20 (top_k order).
__global__ __launch_bounds__(256) void select_kernel(const float* __restrict__ D,
    int* __restrict__ idxout, int q0, int cq){
  __shared__ float cvs[4][72];
  __shared__ int   cxs[4][72];
  int wid = threadIdx.x >> 6;
  int w = blockIdx.x*4 + wid;
  int lane = threadIdx.x & 63;
  int b  = w / cq;
  int qc = w - b*cq;
  int ql = q0 + qc;                  // within-batch query index
  int g  = b*NPB + ql;               // global query node id
  const float* row = D + ((size_t)b*cq + qc) * NPB;
  const float INF = 3.4e38f;
  int qh = ql >> 8, qlw = (ql >> 2) & 63, qe = ql & 3;
  bool dlane = (qlw == lane);
  float4 v[12];
  float a1 = INF, a2 = INF;
  #pragma unroll
  for (int c = 0; c < 12; c++){
    float4 vv = *(const float4*)(row + c*256 + lane*4);
    bool cd = dlane && (qh == c);
    if (cd && qe == 0) vv.x = INF;
    if (cd && qe == 1) vv.y = INF;
    if (cd && qe == 2) vv.z = INF;
    if (cd && qe == 3) vv.w = INF;
    v[c] = vv;
    a2 = fminf(a2, fmaxf(a1, vv.x)); a1 = fminf(a1, vv.x);
    a2 = fminf(a2, fmaxf(a1, vv.y)); a1 = fminf(a1, vv.y);
    a2 = fminf(a2, fmaxf(a1, vv.z)); a1 = fminf(a1, vv.z);
    a2 = fminf(a2, fmaxf(a1, vv.w)); a1 = fminf(a1, vv.w);
  }
  // Phase 2: threshold T
  float T = INF;
  int removed = 0;
  #pragma unroll 1
  for (int r = 0; r < KNN; ++r){
    float m = fminf(a1, a2);
    #pragma unroll
    for (int off = 1; off < 64; off <<= 1) m = fminf(m, __shfl_xor(m, off, 64));
    unsigned long long m1 = __ballot(a1 == m);
    unsigned long long m2 = __ballot(a2 == m);
    removed += __popcll(m1) + __popcll(m2);
    if (a1 == m) a1 = INF;
    if (a2 == m) a2 = INF;
    T = m;
    if (removed >= KNN) break;
  }
  // Phase 3: compact qualifiers (s <= T) into LDS
  float* cv = cvs[wid];
  int*   cx = cxs[wid];
  int base = 0;
  #pragma unroll
  for (int c = 0; c < 12; c++){
    #pragma unroll
    for (int e = 0; e < 4; e++){
      float s = (e==0)?v[c].x:(e==1)?v[c].y:(e==2)?v[c].z:v[c].w;
      bool fire = (s <= T);
      unsigned long long mk = __ballot(fire);
      if (mk){
        int pos = base + (int)__popcll(mk & ((1ull << lane) - 1ull));
        if (fire && pos < 64){ cv[pos] = s; cx[pos] = c*256 + lane*4 + e; }
        base += (int)__popcll(mk);
      }
    }
  }
  if (base <= 64){
    // Phase 4: bitonic sort on u64 lex key
    unsigned long long key;
    if (lane < base){
      unsigned int ku = __float_as_uint(cv[lane]);
      ku ^= (unsigned)(((int)ku) >> 31) | 0x80000000u;
      key = ((unsigned long long)ku << 32) | (unsigned int)cx[lane];
    } else key = ~0ull;
    #pragma unroll
    for (int k = 2; k <= 64; k <<= 1){
      #pragma unroll
      for (int j = k >> 1; j > 0; j >>= 1){
        unsigned long long o = __shfl_xor(key, j, 64);
        bool up    = ((lane & k) == 0);
        bool lower = ((lane & j) == 0);
        unsigned long long mn = key < o ? key : o;
        unsigned long long mx = key < o ? o : key;
        key = (lower == up) ? mn : mx;
      }
    }
    if (lane < KNN)
      idxout[(size_t)g*KNN + lane] = b*NPB + (int)(unsigned int)(key & 0xffffffffu);
  } else {
    // Degenerate-tie fallback: per-lane sorted insert + 20-round wave merge
    float dl[KNN]; int il[KNN];
    #pragma unroll
    for (int k = 0; k < KNN; k++){ dl[k] = INF; il[k] = 0x7fffffff; }
    #pragma unroll
    for (int c = 0; c < 12; c++){
      #pragma unroll
      for (int e = 0; e < 4; e++){
        float s = (e==0)?v[c].x:(e==1)?v[c].y:(e==2)?v[c].z:v[c].w;
        int m = c*256 + lane*4 + e;
        if (s < dl[KNN-1]){
          #pragma unroll
          for (int k = KNN-1; k >= 1; k--){
            bool c1 = s < dl[k-1];
            bool c0 = s < dl[k];
            dl[k] = c1 ? dl[k-1] : (c0 ? s : dl[k]);
            il[k] = c1 ? il[k-1] : (c0 ? m : il[k]);
          }
          if (s < dl[0]){ dl[0] = s; il[0] = m; }
        }
      }
    }
    int res = 0;
    #pragma unroll 1
    for (int r = 0; r < KNN; r++){
      float d = dl[0]; int i = il[0];
      #pragma unroll
      for (int off = 1; off < 64; off <<= 1){
        float od = __shfl_xor(d, off, 64);
        int   oi = __shfl_xor(i, off, 64);
        if (od < d || (od == d && oi < i)){ d = od; i = oi; }
      }
      if (lane == r) res = i;
      if (il[0] == i){
        #pragma unroll
        for (int k = 0; k < KNN-1; k++){ dl[k] = dl[k+1]; il[k] = il[k+1]; }
        dl[KNN-1] = INF; il[KNN-1] = 0x7fffffff;
      }
    }
    if (lane < KNN) idxout[(size_t)g*KNN + lane] = b*NPB + res;
  }
}

// ---------------- legacy fused kNN (fallback when workspace too small) ----------------
__global__ __launch_bounds__(256) void knn_kernel(const float* __restrict__ feat,
    const float* __restrict__ sqn, int* __restrict__ idxout){
  int b  = blockIdx.x / 48;
  int q0 = (blockIdx.x % 48) * 64;
  int t  = threadIdx.x;
  int ty = t >> 4, tx = t & 15;
  __shared__ float As[64][64];
  __shared__ float Bs[64][64];
  __shared__ float Ds[64][68];
  __shared__ float ssq[64];
  const float* fb = feat + (size_t)b*NPB*HD;
  {
    int r = t >> 2, dc = (t & 3)*16;
    const float4* src = (const float4*)(fb + (size_t)(q0 + r)*HD + dc);
    #pragma unroll
    for (int i = 0; i < 4; i++){
      float4 v = src[i]; int d = dc + i*4;
      As[d][r]=v.x; As[d+1][r]=v.y; As[d+2][r]=v.z; As[d+3][r]=v.w;
    }
  }
  float dist[KNN]; int didx[KNN];
  #pragma unroll
  for (int i = 0; i < KNN; i++){ dist[i] = 3.4e38f; didx[i] = 0; }
  int qloc = q0 + t;
  for (int m0 = 0; m0 < NPB; m0 += 64){
    __syncthreads();
    {
      int r = t >> 2, dc = (t & 3)*16;
      const float4* src = (const float4*)(fb + (size_t)(m0 + r)*HD + dc);
      #pragma unroll
      for (int i = 0; i < 4; i++){
        float4 v = src[i]; int d = dc + i*4;
        Bs[d][r]=v.x; Bs[d+1][r]=v.y; Bs[d+2][r]=v.z; Bs[d+3][r]=v.w;
      }
      if (t < 64) ssq[t] = sqn[(size_t)b*NPB + m0 + t];
    }
    __syncthreads();
    float acc[4][4];
    #pragma unroll
    for (int i = 0; i < 4; i++)
      #pragma unroll
      for (int j = 0; j < 4; j++) acc[i][j] = 0.f;
    #pragma unroll 4
    for (int d = 0; d < 64; d++){
      float4 av = *(const float4*)&As[d][ty*4];
      float4 bv = *(const float4*)&Bs[d][tx*4];
      acc[0][0]=fmaf(av.x,bv.x,acc[0][0]); acc[0][1]=fmaf(av.x,bv.y,acc[0][1]);
      acc[0][2]=fmaf(av.x,bv.z,acc[0][2]); acc[0][3]=fmaf(av.x,bv.w,acc[0][3]);
      acc[1][0]=fmaf(av.y,bv.x,acc[1][0]); acc[1][1]=fmaf(av.y,bv.y,acc[1][1]);
      acc[1][2]=fmaf(av.y,bv.z,acc[1][2]); acc[1][3]=fmaf(av.y,bv.w,acc[1][3]);
      acc[2][0]=fmaf(av.z,bv.x,acc[2][0]); acc[2][1]=fmaf(av.z,bv.y,acc[2][1]);
      acc[2][2]=fmaf(av.z,bv.z,acc[2][2]); acc[2][3]=fmaf(av.z,bv.w,acc[2][3]);
      acc[3][0]=fmaf(av.w,bv.x,acc[3][0]); acc[3][1]=fmaf(av.w,bv.y,acc[3][1]);
      acc[3][2]=fmaf(av.w,bv.z,acc[3][2]); acc[3][3]=fmaf(av.w,bv.w,acc[3][3]);
    }
    #pragma unroll
    for (int i = 0; i < 4; i++){
      float4 o; o.x=acc[i][0]; o.y=acc[i][1]; o.z=acc[i][2]; o.w=acc[i][3];
      *(float4*)&Ds[ty*4+i][tx*4] = o;
    }
    __syncthreads();
    if (t < 64){
      #pragma unroll 1
      for (int j = 0; j < 64; j++){
        int m = m0 + j;
        float s = fmaf(-2.f, Ds[t][j], ssq[j]);
        if (m == qloc) continue;
        if (s < dist[KNN-1]){
          #pragma unroll
          for (int k = KNN-1; k >= 1; k--){
            bool sh = s < dist[k-1];
            float nd = sh ? dist[k-1] : (s < dist[k] ? s : dist[k]);
            int   ni = sh ? didx[k-1] : (s < dist[k] ? m : didx[k]);
            dist[k] = nd; didx[k] = ni;
          }
          if (s < dist[0]){ dist[0] = s; didx[0] = m; }
        }
      }
    }
  }
  if (t < 64){
    int* op = idxout + (size_t)((size_t)b*NPB + q0 + t)*KNN;
    #pragma unroll
    for (int k = 0; k < KNN; k++) op[k] = b*NPB + didx[k];
  }
}

// ---------------- edge-conv factorization: u = x@(Wt-Wb)+b, v = x@Wb ----------------
__global__ __launch_bounds__(256) void uv_kernel(const float* __restrict__ feat,
    const float* __restrict__ W, const float* __restrict__ cb,
    float* __restrict__ u, float* __restrict__ v){
  __shared__ float sW[128*64];
  int t = threadIdx.x;
  for (int i = t; i < 8192; i += 256) sW[i] = W[i];
  __syncthreads();
  int n = blockIdx.x*256 + t;
  float4 fv[16];
  const float4* fp = (const float4*)(feat + (size_t)n*64);
  #pragma unroll
  for (int i = 0; i < 16; i++) fv[i] = fp[i];
  float4* up = (float4*)(u + (size_t)n*64);
  float4* vp = (float4*)(v + (size_t)n*64);
  #pragma unroll 1
  for (int c4 = 0; c4 < 16; c4++){
    float ua0=0,ua1=0,ua2=0,ua3=0, vb0=0,vb1=0,vb2=0,vb3=0;
    #pragma unroll
    for (int d4 = 0; d4 < 16; d4++){
      float4 fq = fv[d4];
      #pragma unroll
      for (int dd = 0; dd < 4; dd++){
        int d = d4*4 + dd;
        float fd = dd==0?fq.x : dd==1?fq.y : dd==2?fq.z : fq.w;
        float4 wt = *(const float4*)&sW[d*64 + c4*4];
        float4 wb = *(const float4*)&sW[(64+d)*64 + c4*4];
        ua0=fmaf(fd,wt.x,ua0); ua1=fmaf(fd,wt.y,ua1); ua2=fmaf(fd,wt.z,ua2); ua3=fmaf(fd,wt.w,ua3);
        vb0=fmaf(fd,wb.x,vb0); vb1=fmaf(fd,wb.y,vb1); vb2=fmaf(fd,wb.z,vb2); vb3=fmaf(fd,wb.w,vb3);
      }
    }
    float4 cbv = *(const float4*)&cb[c4*4];
    float4 uo, vo;
    uo.x = cbv.x + ua0 - vb0; uo.y = cbv.y + ua1 - vb1;
    uo.z = cbv.z + ua2 - vb2; uo.w = cbv.w + ua3 - vb3;
    vo.x = vb0; vo.y = vb1; vo.z = vb2; vo.w = vb3;
    up[c4] = uo; vp[c4] = vo;
  }
}

// ---------------- max-pool over k neighbors + BN + residual (one wave per node) ----------------
__global__ __launch_bounds__(256) void pool_kernel(const float* __restrict__ u, const float* __restrict__ v,
    const int* __restrict__ idx, const float* __restrict__ resid,
    const float* __restrict__ bg, const float* __restrict__ bb,
    const float* __restrict__ bm, const float* __restrict__ bv,
    float* __restrict__ out){
  int gid = blockIdx.x*256 + threadIdx.x;
  int n = gid >> 6, lane = gid & 63;
  float uc = u[(size_t)n*64 + lane];
  float scale = bg[lane] / sqrtf(bv[lane] + 1e-5f);
  float bias  = bb[lane] - bm[lane]*scale;
  const int* ip = idx + (size_t)n*KNN;
  float acc = -3.4e38f;
  #pragma unroll 4
  for (int k = 0; k < KNN; k++){
    int j = ip[k];
    float s = uc + v[(size_t)j*64 + lane];
    acc = fmaxf(acc, fmaf(elu_f(s), scale, bias));
  }
  out[(size_t)n*64 + lane] = acc + resid[(size_t)n*64 + lane];
}

// ---------------- CSR build over dst (edges + self loops) ----------------
__global__ void deg_init(int* deg){ int i = blockIdx.x*256 + threadIdx.x; if (i < NTOT) deg[i] = 1; }
__global__ void deg_hist(const int* __restrict__ ei, int E, int* deg){
  int i = blockIdx.x*256 + threadIdx.x; if (i < E) atomicAdd(&deg[ei[E + i]], 1);
}
__global__ void scan_kernel(const int* __restrict__ deg, int* __restrict__ rowptr, int* __restrict__ cursor){
  __shared__ int part[256];
  int t = threadIdx.x;
  int base = t*96;
  int s = 0;
  for (int i = 0; i < 96; i++) s += deg[base + i];
  part[t] = s;
  __syncthreads();
  for (int off = 1; off < 256; off <<= 1){
    int xv = (t >= off) ? part[t - off] : 0;
    __syncthreads();
    part[t] += xv;
    __syncthreads();
  }
  int run = part[t] - s;
  for (int i = 0; i < 96; i++){
    rowptr[base + i] = run; cursor[base + i] = run; run += deg[base + i];
  }
  if (t == 255) rowptr[NTOT] = run;
}
__global__ void scatter_kernel(const int* __restrict__ ei, int E, int* cursor, int* __restrict__ csr){
  int i = blockIdx.x*256 + threadIdx.x;
  if (i >= E + NTOT) return;
  int s, d;
  if (i < E){ s = ei[i]; d = ei[E + i]; } else { s = i - E; d = s; }
  int pos = atomicAdd(&cursor[d], 1);
  csr[pos] = s;
}

// ---------------- GAT: xh = x@W (NT,256), al_s/al_d per head ----------------
__global__ __launch_bounds__(256) void xh_kernel(const float* __restrict__ feat,
    const float* __restrict__ W, const float* __restrict__ asrc, const float* __restrict__ adst,
    float* __restrict__ xh, float* __restrict__ al){
  __shared__ float sW[64*128];
  __shared__ float sas[256], sad[256];
  int t = threadIdx.x;
  if (t < 256){ sas[t] = asrc[t]; sad[t] = adst[t]; }
  int n = blockIdx.x*256 + t;
  float4 fv[16];
  const float4* fp = (const float4*)(feat + (size_t)n*64);
  #pragma unroll
  for (int i = 0; i < 16; i++) fv[i] = fp[i];
  float4* xp = (float4*)(xh + (size_t)n*256);
  float* ap = al + (size_t)n*8;
  #pragma unroll 1
  for (int half = 0; half < 2; half++){
    __syncthreads();
    for (int i = t; i < 8192; i += 256){
      int d = i >> 7, c = i & 127;
      sW[i] = W[d*256 + half*128 + c];
    }
    __syncthreads();
    #pragma unroll 1
    for (int hh = 0; hh < 2; hh++){
      int h = half*2 + hh;
      float as_ = 0.f, ad_ = 0.f;
      #pragma unroll 1
      for (int cc = 0; cc < 64; cc += 4){
        int c  = h*64 + cc;
        int cl = hh*64 + cc;
        float a0=0,a1=0,a2=0,a3=0;
        #pragma unroll
        for (int d4 = 0; d4 < 16; d4++){
          float4 fq = fv[d4];
          #pragma unroll
          for (int dd = 0; dd < 4; dd++){
            int d = d4*4 + dd;
            float fd = dd==0?fq.x : dd==1?fq.y : dd==2?fq.z : fq.w;
            float4 wv = *(const float4*)&sW[d*128 + cl];
            a0=fmaf(fd,wv.x,a0); a1=fmaf(fd,wv.y,a1); a2=fmaf(fd,wv.z,a2); a3=fmaf(fd,wv.w,a3);
          }
        }
        float4 o; o.x=a0; o.y=a1; o.z=a2; o.w=a3;
        xp[c >> 2] = o;
        as_ = fmaf(a0, sas[c], fmaf(a1, sas[c+1], fmaf(a2, sas[c+2], fmaf(a3, sas[c+3], as_))));
        ad_ = fmaf(a0, sad[c], fmaf(a1, sad[c+1], fmaf(a2, sad[c+2], fmaf(a3, sad[c+3], ad_))));
      }
      ap[h] = as_; ap[4 + h] = ad_;
    }
  }
}

// ---------------- GAT aggregation: one-pass online softmax, one wave per dst ----------------
__global__ __launch_bounds__(256) void agg_kernel(const float* __restrict__ xh, const float* __restrict__ al,
    const int* __restrict__ rowptr, const int* __restrict__ csr,
    const float* __restrict__ resid, const float* __restrict__ bias,
    float* __restrict__ out){
  int gid = blockIdx.x*256 + threadIdx.x;
  int n = gid >> 6, lane = gid & 63;
  int rs = rowptr[n], re = rowptr[n+1];
  int h = lane >> 4, coff = (lane & 15)*4;
  float ald_h = al[(size_t)n*8 + 4 + h];
  float mx = -3.4e38f, den = 0.f;
  float ax=0.f, ay=0.f, az=0.f, aw=0.f;
  #pragma unroll 2
  for (int e = rs; e < re; e++){
    int s = csr[e];
    float a = al[(size_t)s*8 + h] + ald_h;
    a = a > 0.f ? a : 0.2f*a;                   // leaky_relu
    float nm = fmaxf(mx, a);
    float corr = __expf(mx - nm);
    float ea   = __expf(a - nm);
    mx = nm;
    float4 xv = *(const float4*)(xh + (size_t)s*256 + h*64 + coff);
    den = fmaf(den, corr, ea);
    ax = fmaf(ax, corr, ea*xv.x); ay = fmaf(ay, corr, ea*xv.y);
    az = fmaf(az, corr, ea*xv.z); aw = fmaf(aw, corr, ea*xv.w);
  }
  float rinv = 1.f / (den + 1e-16f);
  float r0 = ax*rinv, r1 = ay*rinv, r2 = az*rinv, r3 = aw*rinv;
  r0 += __shfl_xor(r0, 16, 64); r1 += __shfl_xor(r1, 16, 64);
  r2 += __shfl_xor(r2, 16, 64); r3 += __shfl_xor(r3, 16, 64);
  r0 += __shfl_xor(r0, 32, 64); r1 += __shfl_xor(r1, 32, 64);
  r2 += __shfl_xor(r2, 32, 64); r3 += __shfl_xor(r3, 32, 64);
  if (lane < 16){
    float4 bs = *(const float4*)(bias + coff);
    float4 rv = *(const float4*)(resid + (size_t)n*64 + coff);
    float4 o;
    o.x = r0*0.25f + bs.x + rv.x; o.y = r1*0.25f + bs.y + rv.y;
    o.z = r2*0.25f + bs.z + rv.z; o.w = r3*0.25f + bs.w + rv.w;
    *(float4*)(out + (size_t)n*64 + coff) = o;
  }
}

// ---------------- output MLP: 64->64 elu ->32 elu ->8 ----------------
__global__ __launch_bounds__(256) void mlp_kernel(const float* __restrict__ feat,
    const float* __restrict__ W1, const float* __restrict__ b1,
    const float* __restrict__ W2, const float* __restrict__ b2,
    const float* __restrict__ W3, const float* __restrict__ b3,
    float* __restrict__ out){
  __shared__ float s1[4096], s2[2048], s3[256], t1[64], t2[32], t3[8];
  int t = threadIdx.x;
  for (int i = t; i < 4096; i += 256) s1[i] = W1[i];
  for (int i = t; i < 2048; i += 256) s2[i] = W2[i];
  if (t < 256) s3[t] = W3[t];
  if (t < 64) t1[t] = b1[t];
  if (t < 32) t2[t] = b2[t];
  if (t < 8)  t3[t] = b3[t];
  __syncthreads();
  int n = blockIdx.x*256 + t;
  float4 fv[16];
  const float4* fp = (const float4*)(feat + (size_t)n*64);
  #pragma unroll
  for (int i = 0; i < 16; i++) fv[i] = fp[i];
  float o1[64];
  #pragma unroll 1
  for (int c4 = 0; c4 < 16; c4++){
    float a0=t1[c4*4+0], a1=t1[c4*4+1], a2=t1[c4*4+2], a3=t1[c4*4+3];
    #pragma unroll
    for (int d4 = 0; d4 < 16; d4++){
      float4 fq = fv[d4];
      #pragma unroll
      for (int dd = 0; dd < 4; dd++){
        int d = d4*4 + dd;
        float fd = dd==0?fq.x : dd==1?fq.y : dd==2?fq.z : fq.w;
        float4 wv = *(const float4*)&s1[d*64 + c4*4];
        a0=fmaf(fd,wv.x,a0); a1=fmaf(fd,wv.y,a1); a2=fmaf(fd,wv.z,a2); a3=fmaf(fd,wv.w,a3);
      }
    }
    o1[c4*4+0]=elu_f(a0); o1[c4*4+1]=elu_f(a1); o1[c4*4+2]=elu_f(a2); o1[c4*4+3]=elu_f(a3);
  }
  float o2[32];
  #pragma unroll 1
  for (int c4 = 0; c4 < 8; c4++){
    float a0=t2[c4*4+0], a1=t2[c4*4+1], a2=t2[c4*4+2], a3=t2[c4*4+3];
    #pragma unroll
    for (int d = 0; d < 64; d++){
      float fd = o1[d];
      float4 wv = *(const float4*)&s2[d*32 + c4*4];
      a0=fmaf(fd,wv.x,a0); a1=fmaf(fd,wv.y,a1); a2=fmaf(fd,wv.z,a2); a3=fmaf(fd,wv.w,a3);
    }
    o2[c4*4+0]=elu_f(a0); o2[c4*4+1]=elu_f(a1); o2[c4*4+2]=elu_f(a2); o2[c4*4+3]=elu_f(a3);
  }
  float4* op = (float4*)(out + (size_t)n*8);
  #pragma unroll
  for (int c4 = 0; c4 < 2; c4++){
    float a0=t3[c4*4+0], a1=t3[c4*4+1], a2=t3[c4*4+2], a3=t3[c4*4+3];
    #pragma unroll
    for (int d = 0; d < 32; d++){
      float fd = o2[d];
      float4 wv = *(const float4*)&s3[d*8 + c4*4];
      a0=fmaf(fd,wv.x,a0); a1=fmaf(fd,wv.y,a1); a2=fmaf(fd,wv.z,a2); a3=fmaf(fd,wv.w,a3);
    }
    float4 o; o.x=a0; o.y=a1; o.z=a2; o.w=a3;
    op[c4] = o;
  }
}

extern "C" void kernel_launch(void* const* d_in, const int* in_sizes, int n_in,
                              void* d_out, int out_size, void* d_ws, size_t ws_size,
                              hipStream_t stream){
  (void)n_in; (void)out_size;
  const float* x     = (const float*)d_in[0];
  const int*   ei    = (const int*)d_in[2];
  const int    E     = in_sizes[2] / 2;
  const float* encW1 = (const float*)d_in[3];
  const float* encb1 = (const float*)d_in[4];
  const float* encW2 = (const float*)d_in[5];
  const float* encb2 = (const float*)d_in[6];
  const float* convW = (const float*)d_in[7];
  const float* convb = (const float*)d_in[8];
  const float* bng   = (const float*)d_in[9];
  const float* bnb   = (const float*)d_in[10];
  const float* bnm   = (const float*)d_in[11];
  const float* bnv   = (const float*)d_in[12];
  const float* gatW  = (const float*)d_in[13];
  const float* gatas = (const float*)d_in[14];
  const float* gatad = (const float*)d_in[15];
  const float* gatb  = (const float*)d_in[16];
  const float* oW1   = (const float*)d_in[17];
  const float* ob1   = (const float*)d_in[18];
  const float* oW2   = (const float*)d_in[19];
  const float* ob2   = (const float*)d_in[20];
  const float* oW3   = (const float*)d_in[21];
  const float* ob3   = (const float*)d_in[22];

  char* wp = (char*)d_ws;
  auto alloc = [&](size_t bytes)->void*{
    void* p = (void*)wp; wp += (bytes + 255) & ~((size_t)255); return p;
  };
  float* fA     = (float*)alloc((size_t)NTOT*64*4);
  float* fB     = (float*)alloc((size_t)NTOT*64*4);
  float* ubuf   = (float*)alloc((size_t)NTOT*64*4);
  float* vbuf   = (float*)alloc((size_t)NTOT*64*4);
  float* sqb    = (float*)alloc((size_t)NTOT*4);
  int*   idxb   = (int*)  alloc((size_t)NTOT*KNN*4);
  float* xhb    = (float*)alloc((size_t)NTOT*256*4);
  float* alb    = (float*)alloc((size_t)NTOT*8*4);
  int*   degb   = (int*)  alloc((size_t)NTOT*4);
  int*   rowptr = (int*)  alloc((size_t)(NTOT+1)*4);
  int*   cursor = (int*)  alloc((size_t)NTOT*4);
  int*   csr    = (int*)  alloc((size_t)(E+NTOT)*4);

  size_t used  = (size_t)(wp - (char*)d_ws);
  size_t avail = ws_size > used ? ws_size - used : 0;
  int CQ = (int)(avail / ((size_t)NB * NPB * sizeof(float)));
  CQ = (CQ / 128) * 128;
  if (CQ > NPB) CQ = NPB;
  float* Dbuf = (float*)wp;

  enc_kernel<<<96,256,0,stream>>>(x, encW1, encb1, encW2, encb2, fA);
  float* cur = fA; float* nxt = fB;
  for (int l = 0; l < 3; l++){
    sq_kernel<<<96,256,0,stream>>>(cur, sqb);
    if (CQ >= 128){
      for (int q0 = 0; q0 < NPB; q0 += CQ){
        int cq = NPB - q0 < CQ ? NPB - q0 : CQ;
        dist_kernel  <<<dim3(24, cq/128, NB),256,0,stream>>>(cur, sqb, Dbuf, q0, cq);
        select_kernel<<<(NB*cq)/4,           256,0,stream>>>(Dbuf, idxb, q0, cq);
      }
    } else {
      knn_kernel<<<384,256,0,stream>>>(cur, sqb, idxb);
    }
    uv_kernel  <<<96,  256,0,stream>>>(cur, convW + (size_t)l*8192, convb + l*64, ubuf, vbuf);
    pool_kernel<<<6144,256,0,stream>>>(ubuf, vbuf, idxb, cur,
                                       bng + l*64, bnb + l*64, bnm + l*64, bnv + l*64, nxt);
    float* tmp = cur; cur = nxt; nxt = tmp;
  }
  deg_init   <<<96,            256,0,stream>>>(degb);
  deg_hist   <<<(E+255)/256,   256,0,stream>>>(ei, E, degb);
  scan_kernel<<<1,             256,0,stream>>>(degb, rowptr, cursor);
  scatter_kernel<<<(E+NTOT+255)/256,256,0,stream>>>(ei, E, cursor, csr);
  for (int l = 0; l < 2; l++){
    xh_kernel <<<96,  256,0,stream>>>(cur, gatW + (size_t)l*16384, gatas + l*256, gatad + l*256, xhb, alb);
    agg_kernel<<<6144,256,0,stream>>>(xhb, alb, rowptr, csr, cur, gatb + l*64, nxt);
    float* tmp = cur; cur = nxt; nxt = tmp;
  }
  mlp_kernel<<<96,256,0,stream>>>(cur, oW1, ob1, oW2, ob2, oW3, ob3, (float*)d_out);
}

// Round 5
// 1249.883 us; speedup vs baseline: 4.5834x; 1.4229x over previous
//
#include <hip/hip_runtime.h>
#include <math.h>

// Problem constants (match reference)
#define NTOT  24576      // B*N nodes
#define NB    8
#define NPB   3072       // nodes per batch
#define HD    64
#define KNN   20

__device__ __forceinline__ float elu_f(float x){ return x > 0.f ? x : expm1f(x); }

// ---------------- encoder: x(NT,8) -> elu(elu(x@W1+b1)@W2+b2) (NT,64) ----------------
__global__ __launch_bounds__(256) void enc_kernel(const float* __restrict__ x,
    const float* __restrict__ W1, const float* __restrict__ b1,
    const float* __restrict__ W2, const float* __restrict__ b2,
    float* __restrict__ out){
  __shared__ float sW1[256], sb1[32], sW2[2048], sb2[64];
  int t = threadIdx.x;
  if (t < 256) sW1[t] = W1[t];
  for (int i = t; i < 2048; i += 256) sW2[i] = W2[i];
  if (t < 32) sb1[t] = b1[t];
  if (t < 64) sb2[t] = b2[t];
  __syncthreads();
  int n = blockIdx.x*256 + t;
  const float4* xp = (const float4*)(x + (size_t)n*8);
  float4 x0 = xp[0], x1 = xp[1];
  float xi[8] = {x0.x,x0.y,x0.z,x0.w,x1.x,x1.y,x1.z,x1.w};
  float h1[32];
  #pragma unroll
  for (int j = 0; j < 32; j++){
    float a = sb1[j];
    #pragma unroll
    for (int d = 0; d < 8; d++) a = fmaf(xi[d], sW1[d*32+j], a);
    h1[j] = elu_f(a);
  }
  float4* op = (float4*)(out + (size_t)n*64);
  #pragma unroll
  for (int c4 = 0; c4 < 16; c4++){
    float a0 = sb2[c4*4+0], a1 = sb2[c4*4+1], a2 = sb2[c4*4+2], a3 = sb2[c4*4+3];
    #pragma unroll
    for (int d = 0; d < 32; d++){
      float hd = h1[d];
      float4 wv = *(const float4*)&sW2[d*64 + c4*4];
      a0 = fmaf(hd, wv.x, a0); a1 = fmaf(hd, wv.y, a1);
      a2 = fmaf(hd, wv.z, a2); a3 = fmaf(hd, wv.w, a3);
    }
    float4 o; o.x=elu_f(a0); o.y=elu_f(a1); o.z=elu_f(a2); o.w=elu_f(a3);
    op[c4] = o;
  }
}

// ---------------- squared norms ----------------
__global__ __launch_bounds__(256) void sq_kernel(const float* __restrict__ f, float* __restrict__ sq){
  int n = blockIdx.x*256 + threadIdx.x;
  const float4* p = (const float4*)(f + (size_t)n*64);
  float s = 0.f;
  #pragma unroll
  for (int i = 0; i < 16; i++){
    float4 v = p[i];
    s = fmaf(v.x,v.x,s); s = fmaf(v.y,v.y,s); s = fmaf(v.z,v.z,s); s = fmaf(v.w,v.w,s);
  }
  sq[n] = s;
}

// ---------------- distance GEMM: s[q][m] = sq[m] - 2*dot(q,m), 128x128 tiles ----------------
__global__ __launch_bounds__(256) void dist_kernel(const float* __restrict__ feat,
    const float* __restrict__ sqn, float* __restrict__ D, int q0, int cq){
  int b  = blockIdx.z;
  int m0 = blockIdx.x * 128;
  int qc0 = blockIdx.y * 128;
  int qg0 = q0 + qc0;
  const float* fb = feat + (size_t)b*NPB*HD;
  float* Db = D + (size_t)b*cq*NPB;
  __shared__ float As[64][128];
  __shared__ float Bs[64][128];
  int t = threadIdx.x;
  {
    int r = t >> 1, dc = (t & 1) * 32;
    const float4* pa = (const float4*)(fb + (size_t)(qg0 + r)*HD + dc);
    const float4* pb = (const float4*)(fb + (size_t)(m0 + r)*HD + dc);
    #pragma unroll
    for (int i = 0; i < 8; i++){
      float4 va = pa[i], vb = pb[i];
      int d = dc + i*4;
      As[d][r]=va.x; As[d+1][r]=va.y; As[d+2][r]=va.z; As[d+3][r]=va.w;
      Bs[d][r]=vb.x; Bs[d+1][r]=vb.y; Bs[d+2][r]=vb.z; Bs[d+3][r]=vb.w;
    }
  }
  __syncthreads();
  int tx = t & 15, ty = t >> 4;
  float acc[8][8];
  #pragma unroll
  for (int i = 0; i < 8; i++)
    #pragma unroll
    for (int j = 0; j < 8; j++) acc[i][j] = 0.f;
  #pragma unroll 2
  for (int d = 0; d < 64; d++){
    float af[8], bf[8];
    *(float4*)&af[0] = *(const float4*)&As[d][ty*8];
    *(float4*)&af[4] = *(const float4*)&As[d][ty*8+4];
    *(float4*)&bf[0] = *(const float4*)&Bs[d][tx*8];
    *(float4*)&bf[4] = *(const float4*)&Bs[d][tx*8+4];
    #pragma unroll
    for (int i = 0; i < 8; i++)
      #pragma unroll
      for (int j = 0; j < 8; j++)
        acc[i][j] = fmaf(af[i], bf[j], acc[i][j]);
  }
  const float4* sp = (const float4*)(sqn + (size_t)b*NPB + m0 + tx*8);
  float4 sq0 = sp[0], sq1 = sp[1];
  float sqv[8] = {sq0.x,sq0.y,sq0.z,sq0.w,sq1.x,sq1.y,sq1.z,sq1.w};
  #pragma unroll
  for (int i = 0; i < 8; i++){
    float* orow = Db + (size_t)(qc0 + ty*8 + i)*NPB + m0 + tx*8;
    float4 o0, o1;
    o0.x = fmaf(-2.f, acc[i][0], sqv[0]); o0.y = fmaf(-2.f, acc[i][1], sqv[1]);
    o0.z = fmaf(-2.f, acc[i][2], sqv[2]); o0.w = fmaf(-2.f, acc[i][3], sqv[3]);
    o1.x = fmaf(-2.f, acc[i][4], sqv[4]); o1.y = fmaf(-2.f, acc[i][5], sqv[5]);
    o1.z = fmaf(-2.f, acc[i][6], sqv[6]); o1.w = fmaf(-2.f, acc[i][7], sqv[7]);
    *(float4*)orow = o0; *((float4*)orow + 1) = o1;
  }
}

// ---------------- top-20 select: LDS row cache + lane-min bitonic threshold ----------------
// One wave per query row. Pass 1: stream row global->LDS, per-lane min a1.
// T = 20th smallest of the 64 lane minima (bitonic sort, 21 stages) >= true v20.
// Pass 2: ballot-compact qualifiers (s <= T) from LDS (superset of true top-20).
// Pass 3: 64-lane bitonic on (monotone_f32<<32|idx) -> exact lex top-20.
__global__ __launch_bounds__(256) void select_kernel(const float* __restrict__ D,
    int* __restrict__ idxout, int q0, int cq){
  __shared__ float srows[4][3072];
  __shared__ float cvs[4][72];
  __shared__ int   cxs[4][72];
  int wid = threadIdx.x >> 6;
  int w = blockIdx.x*4 + wid;
  int lane = threadIdx.x & 63;
  int b  = w / cq;
  int qc = w - b*cq;
  int ql = q0 + qc;                  // within-batch query index
  int g  = b*NPB + ql;               // global query node id
  const float* row = D + ((size_t)b*cq + qc) * NPB;
  const float INF = 3.4e38f;
  int qh = ql >> 8, qlw = (ql >> 2) & 63, qe = ql & 3;
  bool dlane = (qlw == lane);
  float* srow = srows[wid];
  // Pass 1: global -> LDS (diagonal masked), per-lane min
  float a1 = INF;
  #pragma unroll
  for (int c = 0; c < 12; c++){
    float4 vv = *(const float4*)(row + c*256 + lane*4);
    if (dlane && (qh == c)){
      if      (qe == 0) vv.x = INF;
      else if (qe == 1) vv.y = INF;
      else if (qe == 2) vv.z = INF;
      else              vv.w = INF;
    }
    *(float4*)&srow[c*256 + lane*4] = vv;
    a1 = fminf(a1, fminf(fminf(vv.x, vv.y), fminf(vv.z, vv.w)));
  }
  // Threshold: bitonic sort of the 64 lane minima, take 20th smallest
  {
    float v = a1;
    #pragma unroll
    for (int k = 2; k <= 64; k <<= 1){
      #pragma unroll
      for (int j = k >> 1; j > 0; j >>= 1){
        float o = __shfl_xor(v, j, 64);
        bool up    = ((lane & k) == 0);
        bool lower = ((lane & j) == 0);
        float mn = fminf(v, o), mx = fmaxf(v, o);
        v = (lower == up) ? mn : mx;
      }
    }
    a1 = __shfl(v, 19, 64);
  }
  float T = a1;
  // Pass 2: ballot-compact qualifiers from LDS
  float* cv = cvs[wid];
  int*   cx = cxs[wid];
  int base = 0;
  #pragma unroll
  for (int c = 0; c < 12; c++){
    float4 vv = *(const float4*)&srow[c*256 + lane*4];
    #pragma unroll
    for (int e = 0; e < 4; e++){
      float s = (e==0)?vv.x:(e==1)?vv.y:(e==2)?vv.z:vv.w;
      bool fire = (s <= T);
      unsigned long long mk = __ballot(fire);
      if (mk){
        int pos = base + (int)__popcll(mk & ((1ull << lane) - 1ull));
        if (fire && pos < 64){ cv[pos] = s; cx[pos] = c*256 + lane*4 + e; }
        base += (int)__popcll(mk);
      }
    }
  }
  if (base <= 64){
    // Pass 3: bitonic sort on u64 lex key
    unsigned long long key;
    if (lane < base){
      unsigned int ku = __float_as_uint(cv[lane]);
      ku ^= (unsigned)(((int)ku) >> 31) | 0x80000000u;
      key = ((unsigned long long)ku << 32) | (unsigned int)cx[lane];
    } else key = ~0ull;
    #pragma unroll
    for (int k = 2; k <= 64; k <<= 1){
      #pragma unroll
      for (int j = k >> 1; j > 0; j >>= 1){
        unsigned long long o = __shfl_xor(key, j, 64);
        bool up    = ((lane & k) == 0);
        bool lower = ((lane & j) == 0);
        unsigned long long mn = key < o ? key : o;
        unsigned long long mx = key < o ? o : key;
        key = (lower == up) ? mn : mx;
      }
    }
    if (lane < KNN)
      idxout[(size_t)g*KNN + lane] = b*NPB + (int)(unsigned int)(key & 0xffffffffu);
  } else {
    // Degenerate-tie fallback: per-lane sorted insert over LDS + 20-round merge
    float dl[KNN]; int il[KNN];
    #pragma unroll
    for (int k = 0; k < KNN; k++){ dl[k] = INF; il[k] = 0x7fffffff; }
    #pragma unroll 1
    for (int c = 0; c < 12; c++){
      float4 vv = *(const float4*)&srow[c*256 + lane*4];
      #pragma unroll
      for (int e = 0; e < 4; e++){
        float s = (e==0)?vv.x:(e==1)?vv.y:(e==2)?vv.z:vv.w;
        int m = c*256 + lane*4 + e;
        if (s < dl[KNN-1]){
          #pragma unroll
          for (int k = KNN-1; k >= 1; k--){
            bool c1 = s < dl[k-1];
            bool c0 = s < dl[k];
            dl[k] = c1 ? dl[k-1] : (c0 ? s : dl[k]);
            il[k] = c1 ? il[k-1] : (c0 ? m : il[k]);
          }
          if (s < dl[0]){ dl[0] = s; il[0] = m; }
        }
      }
    }
    int res = 0;
    #pragma unroll 1
    for (int r = 0; r < KNN; r++){
      float d = dl[0]; int i = il[0];
      #pragma unroll
      for (int off = 1; off < 64; off <<= 1){
        float od = __shfl_xor(d, off, 64);
        int   oi = __shfl_xor(i, off, 64);
        if (od < d || (od == d && oi < i)){ d = od; i = oi; }
      }
      if (lane == r) res = i;
      if (il[0] == i){
        #pragma unroll
        for (int k = 0; k < KNN-1; k++){ dl[k] = dl[k+1]; il[k] = il[k+1]; }
        dl[KNN-1] = INF; il[KNN-1] = 0x7fffffff;
      }
    }
    if (lane < KNN) idxout[(size_t)g*KNN + lane] = b*NPB + res;
  }
}

// ---------------- legacy fused kNN (fallback when workspace too small) ----------------
__global__ __launch_bounds__(256) void knn_kernel(const float* __restrict__ feat,
    const float* __restrict__ sqn, int* __restrict__ idxout){
  int b  = blockIdx.x / 48;
  int q0 = (blockIdx.x % 48) * 64;
  int t  = threadIdx.x;
  int ty = t >> 4, tx = t & 15;
  __shared__ float As[64][64];
  __shared__ float Bs[64][64];
  __shared__ float Ds[64][68];
  __shared__ float ssq[64];
  const float* fb = feat + (size_t)b*NPB*HD;
  {
    int r = t >> 2, dc = (t & 3)*16;
    const float4* src = (const float4*)(fb + (size_t)(q0 + r)*HD + dc);
    #pragma unroll
    for (int i = 0; i < 4; i++){
      float4 v = src[i]; int d = dc + i*4;
      As[d][r]=v.x; As[d+1][r]=v.y; As[d+2][r]=v.z; As[d+3][r]=v.w;
    }
  }
  float dist[KNN]; int didx[KNN];
  #pragma unroll
  for (int i = 0; i < KNN; i++){ dist[i] = 3.4e38f; didx[i] = 0; }
  int qloc = q0 + t;
  for (int m0 = 0; m0 < NPB; m0 += 64){
    __syncthreads();
    {
      int r = t >> 2, dc = (t & 3)*16;
      const float4* src = (const float4*)(fb + (size_t)(m0 + r)*HD + dc);
      #pragma unroll
      for (int i = 0; i < 4; i++){
        float4 v = src[i]; int d = dc + i*4;
        Bs[d][r]=v.x; Bs[d+1][r]=v.y; Bs[d+2][r]=v.z; Bs[d+3][r]=v.w;
      }
      if (t < 64) ssq[t] = sqn[(size_t)b*NPB + m0 + t];
    }
    __syncthreads();
    float acc[4][4];
    #pragma unroll
    for (int i = 0; i < 4; i++)
      #pragma unroll
      for (int j = 0; j < 4; j++) acc[i][j] = 0.f;
    #pragma unroll 4
    for (int d = 0; d < 64; d++){
      float4 av = *(const float4*)&As[d][ty*4];
      float4 bv = *(const float4*)&Bs[d][tx*4];
      acc[0][0]=fmaf(av.x,bv.x,acc[0][0]); acc[0][1]=fmaf(av.x,bv.y,acc[0][1]);
      acc[0][2]=fmaf(av.x,bv.z,acc[0][2]); acc[0][3]=fmaf(av.x,bv.w,acc[0][3]);
      acc[1][0]=fmaf(av.y,bv.x,acc[1][0]); acc[1][1]=fmaf(av.y,bv.y,acc[1][1]);
      acc[1][2]=fmaf(av.y,bv.z,acc[1][2]); acc[1][3]=fmaf(av.y,bv.w,acc[1][3]);
      acc[2][0]=fmaf(av.z,bv.x,acc[2][0]); acc[2][1]=fmaf(av.z,bv.y,acc[2][1]);
      acc[2][2]=fmaf(av.z,bv.z,acc[2][2]); acc[2][3]=fmaf(av.z,bv.w,acc[2][3]);
      acc[3][0]=fmaf(av.w,bv.x,acc[3][0]); acc[3][1]=fmaf(av.w,bv.y,acc[3][1]);
      acc[3][2]=fmaf(av.w,bv.z,acc[3][2]); acc[3][3]=fmaf(av.w,bv.w,acc[3][3]);
    }
    #pragma unroll
    for (int i = 0; i < 4; i++){
      float4 o; o.x=acc[i][0]; o.y=acc[i][1]; o.z=acc[i][2]; o.w=acc[i][3];
      *(float4*)&Ds[ty*4+i][tx*4] = o;
    }
    __syncthreads();
    if (t < 64){
      #pragma unroll 1
      for (int j = 0; j < 64; j++){
        int m = m0 + j;
        float s = fmaf(-2.f, Ds[t][j], ssq[j]);
        if (m == qloc) continue;
        if (s < dist[KNN-1]){
          #pragma unroll
          for (int k = KNN-1; k >= 1; k--){
            bool sh = s < dist[k-1];
            float nd = sh ? dist[k-1] : (s < dist[k] ? s : dist[k]);
            int   ni = sh ? didx[k-1] : (s < dist[k] ? m : didx[k]);
            dist[k] = nd; didx[k] = ni;
          }
          if (s < dist[0]){ dist[0] = s; didx[0] = m; }
        }
      }
    }
  }
  if (t < 64){
    int* op = idxout + (size_t)((size_t)b*NPB + q0 + t)*KNN;
    #pragma unroll
    for (int k = 0; k < KNN; k++) op[k] = b*NPB + didx[k];
  }
}

// ---------------- edge-conv factorization: u = x@(Wt-Wb)+b, v = x@Wb ----------------
__global__ __launch_bounds__(256) void uv_kernel(const float* __restrict__ feat,
    const float* __restrict__ W, const float* __restrict__ cb,
    float* __restrict__ u, float* __restrict__ v){
  __shared__ float sW[128*64];
  int t = threadIdx.x;
  for (int i = t; i < 8192; i += 256) sW[i] = W[i];
  __syncthreads();
  int n = blockIdx.x*256 + t;
  float4 fv[16];
  const float4* fp = (const float4*)(feat + (size_t)n*64);
  #pragma unroll
  for (int i = 0; i < 16; i++) fv[i] = fp[i];
  float4* up = (float4*)(u + (size_t)n*64);
  float4* vp = (float4*)(v + (size_t)n*64);
  #pragma unroll 1
  for (int c4 = 0; c4 < 16; c4++){
    float ua0=0,ua1=0,ua2=0,ua3=0, vb0=0,vb1=0,vb2=0,vb3=0;
    #pragma unroll
    for (int d4 = 0; d4 < 16; d4++){
      float4 fq = fv[d4];
      #pragma unroll
      for (int dd = 0; dd < 4; dd++){
        int d = d4*4 + dd;
        float fd = dd==0?fq.x : dd==1?fq.y : dd==2?fq.z : fq.w;
        float4 wt = *(const float4*)&sW[d*64 + c4*4];
        float4 wb = *(const float4*)&sW[(64+d)*64 + c4*4];
        ua0=fmaf(fd,wt.x,ua0); ua1=fmaf(fd,wt.y,ua1); ua2=fmaf(fd,wt.z,ua2); ua3=fmaf(fd,wt.w,ua3);
        vb0=fmaf(fd,wb.x,vb0); vb1=fmaf(fd,wb.y,vb1); vb2=fmaf(fd,wb.z,vb2); vb3=fmaf(fd,wb.w,vb3);
      }
    }
    float4 cbv = *(const float4*)&cb[c4*4];
    float4 uo, vo;
    uo.x = cbv.x + ua0 - vb0; uo.y = cbv.y + ua1 - vb1;
    uo.z = cbv.z + ua2 - vb2; uo.w = cbv.w + ua3 - vb3;
    vo.x = vb0; vo.y = vb1; vo.z = vb2; vo.w = vb3;
    up[c4] = uo; vp[c4] = vo;
  }
}

// ---------------- max-pool over k neighbors + BN + residual (one wave per node) ----------------
__global__ __launch_bounds__(256) void pool_kernel(const float* __restrict__ u, const float* __restrict__ v,
    const int* __restrict__ idx, const float* __restrict__ resid,
    const float* __restrict__ bg, const float* __restrict__ bb,
    const float* __restrict__ bm, const float* __restrict__ bv,
    float* __restrict__ out){
  int gid = blockIdx.x*256 + threadIdx.x;
  int n = gid >> 6, lane = gid & 63;
  float uc = u[(size_t)n*64 + lane];
  float scale = bg[lane] / sqrtf(bv[lane] + 1e-5f);
  float bias  = bb[lane] - bm[lane]*scale;
  const int* ip = idx + (size_t)n*KNN;
  float acc = -3.4e38f;
  #pragma unroll 4
  for (int k = 0; k < KNN; k++){
    int j = ip[k];
    float s = uc + v[(size_t)j*64 + lane];
    acc = fmaxf(acc, fmaf(elu_f(s), scale, bias));
  }
  out[(size_t)n*64 + lane] = acc + resid[(size_t)n*64 + lane];
}

// ---------------- CSR build over dst (edges + self loops) ----------------
__global__ void deg_init(int* deg){ int i = blockIdx.x*256 + threadIdx.x; if (i < NTOT) deg[i] = 1; }
__global__ void deg_hist(const int* __restrict__ ei, int E, int* deg){
  int i = blockIdx.x*256 + threadIdx.x; if (i < E) atomicAdd(&deg[ei[E + i]], 1);
}
__global__ void scan_kernel(const int* __restrict__ deg, int* __restrict__ rowptr, int* __restrict__ cursor){
  __shared__ int part[256];
  int t = threadIdx.x;
  int base = t*96;
  int s = 0;
  for (int i = 0; i < 96; i++) s += deg[base + i];
  part[t] = s;
  __syncthreads();
  for (int off = 1; off < 256; off <<= 1){
    int xv = (t >= off) ? part[t - off] : 0;
    __syncthreads();
    part[t] += xv;
    __syncthreads();
  }
  int run = part[t] - s;
  for (int i = 0; i < 96; i++){
    rowptr[base + i] = run; cursor[base + i] = run; run += deg[base + i];
  }
  if (t == 255) rowptr[NTOT] = run;
}
__global__ void scatter_kernel(const int* __restrict__ ei, int E, int* cursor, int* __restrict__ csr){
  int i = blockIdx.x*256 + threadIdx.x;
  if (i >= E + NTOT) return;
  int s, d;
  if (i < E){ s = ei[i]; d = ei[E + i]; } else { s = i - E; d = s; }
  int pos = atomicAdd(&cursor[d], 1);
  csr[pos] = s;
}

// ---------------- GAT: xh = x@W (NT,256), al_s/al_d per head ----------------
__global__ __launch_bounds__(256) void xh_kernel(const float* __restrict__ feat,
    const float* __restrict__ W, const float* __restrict__ asrc, const float* __restrict__ adst,
    float* __restrict__ xh, float* __restrict__ al){
  __shared__ float sW[64*128];
  __shared__ float sas[256], sad[256];
  int t = threadIdx.x;
  if (t < 256){ sas[t] = asrc[t]; sad[t] = adst[t]; }
  int n = blockIdx.x*256 + t;
  float4 fv[16];
  const float4* fp = (const float4*)(feat + (size_t)n*64);
  #pragma unroll
  for (int i = 0; i < 16; i++) fv[i] = fp[i];
  float4* xp = (float4*)(xh + (size_t)n*256);
  float* ap = al + (size_t)n*8;
  #pragma unroll 1
  for (int half = 0; half < 2; half++){
    __syncthreads();
    for (int i = t; i < 8192; i += 256){
      int d = i >> 7, c = i & 127;
      sW[i] = W[d*256 + half*128 + c];
    }
    __syncthreads();
    #pragma unroll 1
    for (int hh = 0; hh < 2; hh++){
      int h = half*2 + hh;
      float as_ = 0.f, ad_ = 0.f;
      #pragma unroll 1
      for (int cc = 0; cc < 64; cc += 4){
        int c  = h*64 + cc;
        int cl = hh*64 + cc;
        float a0=0,a1=0,a2=0,a3=0;
        #pragma unroll
        for (int d4 = 0; d4 < 16; d4++){
          float4 fq = fv[d4];
          #pragma unroll
          for (int dd = 0; dd < 4; dd++){
            int d = d4*4 + dd;
            float fd = dd==0?fq.x : dd==1?fq.y : dd==2?fq.z : fq.w;
            float4 wv = *(const float4*)&sW[d*128 + cl];
            a0=fmaf(fd,wv.x,a0); a1=fmaf(fd,wv.y,a1); a2=fmaf(fd,wv.z,a2); a3=fmaf(fd,wv.w,a3);
          }
        }
        float4 o; o.x=a0; o.y=a1; o.z=a2; o.w=a3;
        xp[c >> 2] = o;
        as_ = fmaf(a0, sas[c], fmaf(a1, sas[c+1], fmaf(a2, sas[c+2], fmaf(a3, sas[c+3], as_))));
        ad_ = fmaf(a0, sad[c], fmaf(a1, sad[c+1], fmaf(a2, sad[c+2], fmaf(a3, sad[c+3], ad_))));
      }
      ap[h] = as_; ap[4 + h] = ad_;
    }
  }
}

// ---------------- GAT aggregation: one-pass online softmax, one wave per dst ----------------
__global__ __launch_bounds__(256) void agg_kernel(const float* __restrict__ xh, const float* __restrict__ al,
    const int* __restrict__ rowptr, const int* __restrict__ csr,
    const float* __restrict__ resid, const float* __restrict__ bias,
    float* __restrict__ out){
  int gid = blockIdx.x*256 + threadIdx.x;
  int n = gid >> 6, lane = gid & 63;
  int rs = rowptr[n], re = rowptr[n+1];
  int h = lane >> 4, coff = (lane & 15)*4;
  float ald_h = al[(size_t)n*8 + 4 + h];
  float mx = -3.4e38f, den = 0.f;
  float ax=0.f, ay=0.f, az=0.f, aw=0.f;
  #pragma unroll 2
  for (int e = rs; e < re; e++){
    int s = csr[e];
    float a = al[(size_t)s*8 + h] + ald_h;
    a = a > 0.f ? a : 0.2f*a;                   // leaky_relu
    float nm = fmaxf(mx, a);
    float corr = __expf(mx - nm);
    float ea   = __expf(a - nm);
    mx = nm;
    float4 xv = *(const float4*)(xh + (size_t)s*256 + h*64 + coff);
    den = fmaf(den, corr, ea);
    ax = fmaf(ax, corr, ea*xv.x); ay = fmaf(ay, corr, ea*xv.y);
    az = fmaf(az, corr, ea*xv.z); aw = fmaf(aw, corr, ea*xv.w);
  }
  float rinv = 1.f / (den + 1e-16f);
  float r0 = ax*rinv, r1 = ay*rinv, r2 = az*rinv, r3 = aw*rinv;
  r0 += __shfl_xor(r0, 16, 64); r1 += __shfl_xor(r1, 16, 64);
  r2 += __shfl_xor(r2, 16, 64); r3 += __shfl_xor(r3, 16, 64);
  r0 += __shfl_xor(r0, 32, 64); r1 += __shfl_xor(r1, 32, 64);
  r2 += __shfl_xor(r2, 32, 64); r3 += __shfl_xor(r3, 32, 64);
  if (lane < 16){
    float4 bs = *(const float4*)(bias + coff);
    float4 rv = *(const float4*)(resid + (size_t)n*64 + coff);
    float4 o;
    o.x = r0*0.25f + bs.x + rv.x; o.y = r1*0.25f + bs.y + rv.y;
    o.z = r2*0.25f + bs.z + rv.z; o.w = r3*0.25f + bs.w + rv.w;
    *(float4*)(out + (size_t)n*64 + coff) = o;
  }
}

// ---------------- output MLP: 64->64 elu ->32 elu ->8 ----------------
__global__ __launch_bounds__(256) void mlp_kernel(const float* __restrict__ feat,
    const float* __restrict__ W1, const float* __restrict__ b1,
    const float* __restrict__ W2, const float* __restrict__ b2,
    const float* __restrict__ W3, const float* __restrict__ b3,
    float* __restrict__ out){
  __shared__ float s1[4096], s2[2048], s3[256], t1[64], t2[32], t3[8];
  int t = threadIdx.x;
  for (int i = t; i < 4096; i += 256) s1[i] = W1[i];
  for (int i = t; i < 2048; i += 256) s2[i] = W2[i];
  if (t < 256) s3[t] = W3[t];
  if (t < 64) t1[t] = b1[t];
  if (t < 32) t2[t] = b2[t];
  if (t < 8)  t3[t] = b3[t];
  __syncthreads();
  int n = blockIdx.x*256 + t;
  float4 fv[16];
  const float4* fp = (const float4*)(feat + (size_t)n*64);
  #pragma unroll
  for (int i = 0; i < 16; i++) fv[i] = fp[i];
  float o1[64];
  #pragma unroll 1
  for (int c4 = 0; c4 < 16; c4++){
    float a0=t1[c4*4+0], a1=t1[c4*4+1], a2=t1[c4*4+2], a3=t1[c4*4+3];
    #pragma unroll
    for (int d4 = 0; d4 < 16; d4++){
      float4 fq = fv[d4];
      #pragma unroll
      for (int dd = 0; dd < 4; dd++){
        int d = d4*4 + dd;
        float fd = dd==0?fq.x : dd==1?fq.y : dd==2?fq.z : fq.w;
        float4 wv = *(const float4*)&s1[d*64 + c4*4];
        a0=fmaf(fd,wv.x,a0); a1=fmaf(fd,wv.y,a1); a2=fmaf(fd,wv.z,a2); a3=fmaf(fd,wv.w,a3);
      }
    }
    o1[c4*4+0]=elu_f(a0); o1[c4*4+1]=elu_f(a1); o1[c4*4+2]=elu_f(a2); o1[c4*4+3]=elu_f(a3);
  }
  float o2[32];
  #pragma unroll 1
  for (int c4 = 0; c4 < 8; c4++){
    float a0=t2[c4*4+0], a1=t2[c4*4+1], a2=t2[c4*4+2], a3=t2[c4*4+3];
    #pragma unroll
    for (int d = 0; d < 64; d++){
      float fd = o1[d];
      float4 wv = *(const float4*)&s2[d*32 + c4*4];
      a0=fmaf(fd,wv.x,a0); a1=fmaf(fd,wv.y,a1); a2=fmaf(fd,wv.z,a2); a3=fmaf(fd,wv.w,a3);
    }
    o2[c4*4+0]=elu_f(a0); o2[c4*4+1]=elu_f(a1); o2[c4*4+2]=elu_f(a2); o2[c4*4+3]=elu_f(a3);
  }
  float4* op = (float4*)(out + (size_t)n*8);
  #pragma unroll
  for (int c4 = 0; c4 < 2; c4++){
    float a0=t3[c4*4+0], a1=t3[c4*4+1], a2=t3[c4*4+2], a3=t3[c4*4+3];
    #pragma unroll
    for (int d = 0; d < 32; d++){
      float fd = o2[d];
      float4 wv = *(const float4*)&s3[d*8 + c4*4];
      a0=fmaf(fd,wv.x,a0); a1=fmaf(fd,wv.y,a1); a2=fmaf(fd,wv.z,a2); a3=fmaf(fd,wv.w,a3);
    }
    float4 o; o.x=a0; o.y=a1; o.z=a2; o.w=a3;
    op[c4] = o;
  }
}

extern "C" void kernel_launch(void* const* d_in, const int* in_sizes, int n_in,
                              void* d_out, int out_size, void* d_ws, size_t ws_size,
                              hipStream_t stream){
  (void)n_in; (void)out_size;
  const float* x     = (const float*)d_in[0];
  const int*   ei    = (const int*)d_in[2];
  const int    E     = in_sizes[2] / 2;
  const float* encW1 = (const float*)d_in[3];
  const float* encb1 = (const float*)d_in[4];
  const float* encW2 = (const float*)d_in[5];
  const float* encb2 = (const float*)d_in[6];
  const float* convW = (const float*)d_in[7];
  const float* convb = (const float*)d_in[8];
  const float* bng   = (const float*)d_in[9];
  const float* bnb   = (const float*)d_in[10];
  const float* bnm   = (const float*)d_in[11];
  const float* bnv   = (const float*)d_in[12];
  const float* gatW  = (const float*)d_in[13];
  const float* gatas = (const float*)d_in[14];
  const float* gatad = (const float*)d_in[15];
  const float* gatb  = (const float*)d_in[16];
  const float* oW1   = (const float*)d_in[17];
  const float* ob1   = (const float*)d_in[18];
  const float* oW2   = (const float*)d_in[19];
  const float* ob2   = (const float*)d_in[20];
  const float* oW3   = (const float*)d_in[21];
  const float* ob3   = (const float*)d_in[22];

  char* wp = (char*)d_ws;
  auto alloc = [&](size_t bytes)->void*{
    void* p = (void*)wp; wp += (bytes + 255) & ~((size_t)255); return p;
  };
  float* fA     = (float*)alloc((size_t)NTOT*64*4);
  float* fB     = (float*)alloc((size_t)NTOT*64*4);
  float* ubuf   = (float*)alloc((size_t)NTOT*64*4);
  float* vbuf   = (float*)alloc((size_t)NTOT*64*4);
  float* sqb    = (float*)alloc((size_t)NTOT*4);
  int*   idxb   = (int*)  alloc((size_t)NTOT*KNN*4);
  float* xhb    = (float*)alloc((size_t)NTOT*256*4);
  float* alb    = (float*)alloc((size_t)NTOT*8*4);
  int*   degb   = (int*)  alloc((size_t)NTOT*4);
  int*   rowptr = (int*)  alloc((size_t)(NTOT+1)*4);
  int*   cursor = (int*)  alloc((size_t)NTOT*4);
  int*   csr    = (int*)  alloc((size_t)(E+NTOT)*4);

  size_t used  = (size_t)(wp - (char*)d_ws);
  size_t avail = ws_size > used ? ws_size - used : 0;
  int CQ = (int)(avail / ((size_t)NB * NPB * sizeof(float)));
  CQ = (CQ / 128) * 128;
  if (CQ > NPB) CQ = NPB;
  float* Dbuf = (float*)wp;

  enc_kernel<<<96,256,0,stream>>>(x, encW1, encb1, encW2, encb2, fA);
  float* cur = fA; float* nxt = fB;
  for (int l = 0; l < 3; l++){
    sq_kernel<<<96,256,0,stream>>>(cur, sqb);
    if (CQ >= 128){
      for (int q0 = 0; q0 < NPB; q0 += CQ){
        int cq = NPB - q0 < CQ ? NPB - q0 : CQ;
        dist_kernel  <<<dim3(24, cq/128, NB),256,0,stream>>>(cur, sqb, Dbuf, q0, cq);
        select_kernel<<<(NB*cq)/4,           256,0,stream>>>(Dbuf, idxb, q0, cq);
      }
    } else {
      knn_kernel<<<384,256,0,stream>>>(cur, sqb, idxb);
    }
    uv_kernel  <<<96,  256,0,stream>>>(cur, convW + (size_t)l*8192, convb + l*64, ubuf, vbuf);
    pool_kernel<<<6144,256,0,stream>>>(ubuf, vbuf, idxb, cur,
                                       bng + l*64, bnb + l*64, bnm + l*64, bnv + l*64, nxt);
    float* tmp = cur; cur = nxt; nxt = tmp;
  }
  deg_init   <<<96,            256,0,stream>>>(degb);
  deg_hist   <<<(E+255)/256,   256,0,stream>>>(ei, E, degb);
  scan_kernel<<<1,             256,0,stream>>>(degb, rowptr, cursor);
  scatter_kernel<<<(E+NTOT+255)/256,256,0,stream>>>(ei, E, cursor, csr);
  for (int l = 0; l < 2; l++){
    xh_kernel <<<96,  256,0,stream>>>(cur, gatW + (size_t)l*16384, gatas + l*256, gatad + l*256, xhb, alb);
    agg_kernel<<<6144,256,0,stream>>>(xhb, alb, rowptr, csr, cur, gatb + l*64, nxt);
    float* tmp = cur; cur = nxt; nxt = tmp;
  }
  mlp_kernel<<<96,256,0,stream>>>(cur, oW1, ob1, oW2, ob2, oW3, ob3, (float*)d_out);
}